// Round 1
// 2493.573 us; speedup vs baseline: 1.0862x; 1.0862x over previous
//
#include <hip/hip_runtime.h>
#include <math.h>

#define NNODES 10000
#define NEDGES 50000
#define ND 1152
#define MUL 128
#define WNW 1408
#define EDIM 20

#define CK1 0.5773502691896258f
#define CK2 0.4472135954999579f
#define A2C 0.31622776601683794f
#define A0A (-0.18257418583505536f)
#define A0B 0.3651483716701107f
#define B1C 0.11952286093343936f
#define B2C 0.23904572186687873f
#define B3C 0.20701966780270626f
#define PW0 0.5773502691896258f
#define PW1 0.8660254037844386f
#define PW2 1.1180339887498949f
#define INV128 0.08838834764831845f

__device__ __forceinline__ float silu_f(float v) { return v / (1.f + expf(-v)); }

// ============================================================================
// 128x128-tile fp32 GEMM, 256 threads, 8x8 micro-tile (2x2 blocks of 4x4),
// A transposed in LDS so all fragment reads are ds_read_b128.
// AMODE 0: plain A[lda]. 1: s0 edge assembly (gather x + dots), K=512.
//       2: strided o3 component read from interleaved x (off/stride by z).
//       3: plane A (A += z*M*lda).
//       4: plane A fused with norm-gate: z==0 -> A = g[:, :128] (fij unused);
//          z 1..3 -> fij_plane * g[:,128+u]; z 4..8 -> fij_plane * g[:,256+u].
//          gate matrix passed via xg (row stride 384).
// OMODE 0: plain C[ldc]. 1: strided o3 component write to interleaved out.
//       2: plane C (C += z*M*ldc).
// O3S: scale INV128 (+ bias at z==0 only). SILU / FMUL epilogue fusions.
// ============================================================================
template<int AMODE, int OMODE, bool SILU, bool FMUL, bool O3S>
__global__ __launch_bounds__(256) void gemm128(
    const float* __restrict__ A, int lda,
    const float* __restrict__ B, int ldb,
    const float* __restrict__ W1p, const float* __restrict__ W2p,
    const float* __restrict__ bias, const float* __restrict__ M2,
    float* __restrict__ C, int ldc, int M, int K,
    const float* __restrict__ xg, const int* __restrict__ ei,
    const float* __restrict__ dots)
{
    __shared__ float Ast[32][132];
    __shared__ float Bs[32][132];

    const int tid = threadIdx.x;
    const int tx = tid & 15, ty = tid >> 4;
    const int rowBase = blockIdx.y << 7;
    const int n0 = blockIdx.x << 7;
    const int z = blockIdx.z;

    int off = 0, stride = 1;
    if constexpr (AMODE == 2 || AMODE == 3 || AMODE == 4 || OMODE == 1 || O3S) {
        if (z == 0)      { off = 0;             stride = 1; }
        else if (z < 4)  { off = 128 + (z - 1); stride = 3; }
        else             { off = 512 + (z - 4); stride = 5; }
    }
    const float* Bz = B;
    if constexpr (AMODE >= 2) {   // o3 weight select by l
        if (z >= 1 && z < 4) Bz = W1p;
        else if (z >= 4)     Bz = W2p;
    }
    const float* Ab = A;
    if constexpr (AMODE == 3 || AMODE == 4) Ab = A + (size_t)z * M * lda;
    float* Cb = C;
    if constexpr (OMODE == 2) Cb = C + (size_t)z * M * ldc;

    float acc[2][2][4][4] = {};

    for (int k0 = 0; k0 < K; k0 += 32) {
        // ---- stage A (transposed into LDS) ----
#pragma unroll
        for (int i = 0; i < 4; ++i) {
            int f4 = tid + (i << 8);          // 0..1023
            int row = f4 >> 3;                // 0..127
            int kq  = (f4 & 7) << 2;          // 0,4,..,28
            int grow = rowBase + row, gk = k0 + kq;
            float4 v = make_float4(0.f, 0.f, 0.f, 0.f);
            if (grow < M) {
                if constexpr (AMODE == 0 || AMODE == 3) {
                    if (gk + 4 <= K) {
                        v = *(const float4*)&Ab[(size_t)grow * lda + gk];
                    } else {
                        float t[4] = {0.f, 0.f, 0.f, 0.f};
#pragma unroll
                        for (int j = 0; j < 4; ++j)
                            if (gk + j < K) t[j] = Ab[(size_t)grow * lda + gk + j];
                        v = make_float4(t[0], t[1], t[2], t[3]);
                    }
                } else if constexpr (AMODE == 1) {
                    if (gk < 128)
                        v = *(const float4*)&xg[(size_t)ei[grow] * ND + gk];
                    else if (gk < 256)
                        v = *(const float4*)&xg[(size_t)ei[NEDGES + grow] * ND + (gk - 128)];
                    else
                        v = *(const float4*)&dots[(size_t)grow * 256 + (gk - 256)];
                } else if constexpr (AMODE == 2) {  // strided component from interleaved rows
                    const float* p = &Ab[(size_t)grow * ND + off];
                    v.x = p[(gk + 0) * stride];
                    v.y = p[(gk + 1) * stride];
                    v.z = p[(gk + 2) * stride];
                    v.w = p[(gk + 3) * stride];
                } else {  // AMODE 4: gated plane read
                    int gsel = (z == 0) ? 0 : (z < 4 ? 128 : 256);
                    float4 vg = *(const float4*)&xg[(size_t)grow * 384 + gsel + gk];
                    if (z == 0) {
                        v = vg;
                    } else {
                        float4 vf = *(const float4*)&Ab[(size_t)grow * lda + gk];
                        v = make_float4(vf.x * vg.x, vf.y * vg.y,
                                        vf.z * vg.z, vf.w * vg.w);
                    }
                }
            }
            Ast[kq + 0][row] = v.x;
            Ast[kq + 1][row] = v.y;
            Ast[kq + 2][row] = v.z;
            Ast[kq + 3][row] = v.w;
        }
        // ---- stage B ----
#pragma unroll
        for (int i = 0; i < 4; ++i) {
            int f4 = tid + (i << 8);
            int bk = f4 >> 5;                 // 0..31
            int nq = (f4 & 31) << 2;          // 0..124
            float4 v = make_float4(0.f, 0.f, 0.f, 0.f);
            if (k0 + bk < K)
                v = *(const float4*)&Bz[(size_t)(k0 + bk) * ldb + n0 + nq];
            *(float4*)&Bs[bk][nq] = v;
        }
        __syncthreads();
#pragma unroll
        for (int kk = 0; kk < 32; ++kk) {
            float4 a0 = *(const float4*)&Ast[kk][(ty << 2)];
            float4 a1 = *(const float4*)&Ast[kk][64 + (ty << 2)];
            float4 b0 = *(const float4*)&Bs[kk][(tx << 2)];
            float4 b1 = *(const float4*)&Bs[kk][64 + (tx << 2)];
            float ar[2][4] = {{a0.x, a0.y, a0.z, a0.w}, {a1.x, a1.y, a1.z, a1.w}};
            float br[2][4] = {{b0.x, b0.y, b0.z, b0.w}, {b1.x, b1.y, b1.z, b1.w}};
#pragma unroll
            for (int h = 0; h < 2; ++h)
#pragma unroll
                for (int g = 0; g < 2; ++g)
#pragma unroll
                    for (int ii = 0; ii < 4; ++ii)
#pragma unroll
                        for (int jj = 0; jj < 4; ++jj)
                            acc[h][g][ii][jj] = fmaf(ar[h][ii], br[g][jj], acc[h][g][ii][jj]);
        }
        __syncthreads();
    }

    // ---- epilogue ----
#pragma unroll
    for (int h = 0; h < 2; ++h) {
#pragma unroll
        for (int ii = 0; ii < 4; ++ii) {
            int row = rowBase + (h << 6) + (ty << 2) + ii;
            if (row >= M) continue;
#pragma unroll
            for (int g = 0; g < 2; ++g) {
                int colq = n0 + (g << 6) + (tx << 2);
                float o[4];
#pragma unroll
                for (int jj = 0; jj < 4; ++jj) {
                    float v = acc[h][g][ii][jj];
                    int col = colq + jj;
                    if constexpr (O3S) {
                        v *= INV128;
                        if (bias && z == 0) v += bias[col];
                    } else {
                        if (bias) v += bias[col];
                    }
                    if constexpr (SILU) v = silu_f(v);
                    if constexpr (FMUL) v *= M2[(size_t)row * ldc + col];
                    o[jj] = v;
                }
                if constexpr (OMODE == 1) {
                    float* p = &Cb[(size_t)row * ND + off];
#pragma unroll
                    for (int jj = 0; jj < 4; ++jj) p[(colq + jj) * stride] = o[jj];
                } else {
                    *(float4*)&Cb[(size_t)row * ldc + colq] =
                        make_float4(o[0], o[1], o[2], o[3]);
                }
            }
        }
    }
}

// ============================================================================
// Fused tp-weight kernel: tpw = (hes @ es_W2 + es_b2) * (her @ er_W2 + er_b2).
// Same 128x128 tile / 8x8 micro-tile engine as gemm128, but runs the K=128
// loop twice (phase 0: es, phase 1: er), stashing phase-0 result (+bias) in
// registers. Eliminates the 281 MB es2c HBM write + re-read and one full
// GEMM pass. K fixed at 128, N fixed at WNW (grid.x = 11 exactly).
// ============================================================================
__global__ __launch_bounds__(256) void w2fused(
    const float* __restrict__ A1, const float* __restrict__ B1,
    const float* __restrict__ b1,
    const float* __restrict__ A2, const float* __restrict__ B2,
    const float* __restrict__ b2,
    float* __restrict__ C, int M)
{
    __shared__ float Ast[32][132];
    __shared__ float Bs[32][132];

    const int tid = threadIdx.x;
    const int tx = tid & 15, ty = tid >> 4;
    const int rowBase = blockIdx.y << 7;
    const int n0 = blockIdx.x << 7;

    float acc1[2][2][4][4];
    float acc[2][2][4][4] = {};

#pragma unroll
    for (int ph = 0; ph < 2; ++ph) {
        const float* A = ph ? A2 : A1;
        const float* B = ph ? B2 : B1;
        for (int k0 = 0; k0 < 128; k0 += 32) {
            // ---- stage A (transposed) ----
#pragma unroll
            for (int i = 0; i < 4; ++i) {
                int f4 = tid + (i << 8);
                int row = f4 >> 3;
                int kq  = (f4 & 7) << 2;
                int grow = rowBase + row;
                float4 v = make_float4(0.f, 0.f, 0.f, 0.f);
                if (grow < M)
                    v = *(const float4*)&A[(size_t)grow * 128 + k0 + kq];
                Ast[kq + 0][row] = v.x;
                Ast[kq + 1][row] = v.y;
                Ast[kq + 2][row] = v.z;
                Ast[kq + 3][row] = v.w;
            }
            // ---- stage B ----
#pragma unroll
            for (int i = 0; i < 4; ++i) {
                int f4 = tid + (i << 8);
                int bk = f4 >> 5;
                int nq = (f4 & 31) << 2;
                *(float4*)&Bs[bk][nq] =
                    *(const float4*)&B[(size_t)(k0 + bk) * WNW + n0 + nq];
            }
            __syncthreads();
#pragma unroll
            for (int kk = 0; kk < 32; ++kk) {
                float4 a0 = *(const float4*)&Ast[kk][(ty << 2)];
                float4 a1 = *(const float4*)&Ast[kk][64 + (ty << 2)];
                float4 b0 = *(const float4*)&Bs[kk][(tx << 2)];
                float4 b1v = *(const float4*)&Bs[kk][64 + (tx << 2)];
                float ar[2][4] = {{a0.x, a0.y, a0.z, a0.w}, {a1.x, a1.y, a1.z, a1.w}};
                float br[2][4] = {{b0.x, b0.y, b0.z, b0.w}, {b1v.x, b1v.y, b1v.z, b1v.w}};
#pragma unroll
                for (int h = 0; h < 2; ++h)
#pragma unroll
                    for (int g = 0; g < 2; ++g)
#pragma unroll
                        for (int ii = 0; ii < 4; ++ii)
#pragma unroll
                            for (int jj = 0; jj < 4; ++jj)
                                acc[h][g][ii][jj] =
                                    fmaf(ar[h][ii], br[g][jj], acc[h][g][ii][jj]);
            }
            __syncthreads();
        }
        if (ph == 0) {
            // stash phase-0 result (+bias), reset accumulator
#pragma unroll
            for (int h = 0; h < 2; ++h)
#pragma unroll
                for (int g = 0; g < 2; ++g) {
                    int colq = n0 + (g << 6) + (tx << 2);
#pragma unroll
                    for (int ii = 0; ii < 4; ++ii)
#pragma unroll
                        for (int jj = 0; jj < 4; ++jj) {
                            acc1[h][g][ii][jj] = acc[h][g][ii][jj] + b1[colq + jj];
                            acc[h][g][ii][jj] = 0.f;
                        }
                }
        }
    }

    // ---- epilogue: C = acc1 * (acc + b2) ----
#pragma unroll
    for (int h = 0; h < 2; ++h) {
#pragma unroll
        for (int ii = 0; ii < 4; ++ii) {
            int row = rowBase + (h << 6) + (ty << 2) + ii;
            if (row >= M) continue;
#pragma unroll
            for (int g = 0; g < 2; ++g) {
                int colq = n0 + (g << 6) + (tx << 2);
                float4 o;
                o.x = acc1[h][g][ii][0] * (acc[h][g][ii][0] + b2[colq + 0]);
                o.y = acc1[h][g][ii][1] * (acc[h][g][ii][1] + b2[colq + 1]);
                o.z = acc1[h][g][ii][2] * (acc[h][g][ii][2] + b2[colq + 2]);
                o.w = acc1[h][g][ii][3] * (acc[h][g][ii][3] + b2[colq + 3]);
                *(float4*)&C[(size_t)row * WNW + colq] = o;
            }
        }
    }
}

// ============================================================================
// dots for s0 (reads interleaved input x)
// ============================================================================
__global__ void dots_kernel(const float* __restrict__ x, const int* __restrict__ ei,
                            float* __restrict__ dots)
{
    int idx = blockIdx.x * 256 + threadIdx.x;
    int e = idx >> 8, t = idx & 255;
    if (e >= NEDGES) return;
    const float* ps = x + (size_t)ei[e] * ND;
    const float* pd = x + (size_t)ei[NEDGES + e] * ND;
    float v;
    if (t < 128) {
        int u = 128 + t * 3;
        v = (ps[u] * pd[u] + ps[u + 1] * pd[u + 1] + ps[u + 2] * pd[u + 2]) * CK1;
    } else {
        int u = 512 + (t - 128) * 5;
        v = (ps[u] * pd[u] + ps[u + 1] * pd[u + 1] + ps[u + 2] * pd[u + 2]
             + ps[u + 3] * pd[u + 3] + ps[u + 4] * pd[u + 4]) * CK2;
    }
    dots[idx] = v;
}

// ============================================================================
// f0 = [s, ||v1||_c, ||v2||_c] from PLANE layout (plane stride M*128)
// (node-side only now; edge-side f0 is fused into tp_kernel)
// ============================================================================
__global__ void f0_kernel(const float* __restrict__ in, float* __restrict__ f0, int M)
{
    int idx = blockIdx.x * 256 + threadIdx.x;
    int r = idx / 384, t = idx - r * 384;
    if (r >= M) return;
    size_t P = (size_t)M * 128;
    const float* p = in + (size_t)r * 128;
    float v;
    if (t < 128) v = p[t];
    else if (t < 256) {
        int u = t - 128;
        float x1 = p[P + u], x2 = p[2 * P + u], x3 = p[3 * P + u];
        v = sqrtf(x1 * x1 + x2 * x2 + x3 * x3);
    } else {
        int u = t - 256;
        float x1 = p[4 * P + u], x2 = p[5 * P + u], x3 = p[6 * P + u],
              x4 = p[7 * P + u], x5 = p[8 * P + u];
        v = sqrtf(x1 * x1 + x2 * x2 + x3 * x3 + x4 * x4 + x5 * x5);
    }
    f0[(size_t)r * 384 + t] = v;
}

// gate in place on PLANE layout (node-side only now). grid: (ceil(M*128/256), 9)
__global__ void gate_kernel(float* __restrict__ xp, const float* __restrict__ g, int M)
{
    int t = blockIdx.x * 256 + threadIdx.x;
    if (t >= M * 128) return;
    int z = blockIdx.y;
    int r = t >> 7, u = t & 127;
    float* p = xp + (size_t)z * M * 128 + t;
    const float* gr = g + (size_t)r * 384;
    if (z == 0)      *p = gr[u];
    else if (z < 4)  *p *= gr[128 + u];
    else             *p *= gr[256 + u];
}

// ============================================================================
// Wigner TP, plane layout in (xp) and out (fij). 2 edges per block.
// Also emits f0 = [o_s, ||o1||, ||o2||] directly (fuses the edge f0 pass).
// ============================================================================
__global__ __launch_bounds__(256) void tp_kernel(
    const float* __restrict__ xp, const int* __restrict__ ei,
    const float* __restrict__ tpw, float* __restrict__ fij,
    float* __restrict__ f0, int e0, int ec)
{
    int le = blockIdx.x * 2 + (threadIdx.x >> 7);
    int u = threadIdx.x & 127;
    if (le >= ec) return;
    int e = e0 + le;
    const size_t NP = (size_t)NNODES * 128;
    const float* ps = xp + (size_t)ei[e] * 128 + u;
    const float* pd = xp + (size_t)ei[NEDGES + e] * 128 + u;

    float ss = ps[0], sd = pd[0];
    float a0 = ps[NP],     a1 = ps[2 * NP], a2 = ps[3 * NP];
    float b0 = pd[NP],     b1 = pd[2 * NP], b2 = pd[3 * NP];
    float c0 = ps[4 * NP], c1 = ps[5 * NP], c2 = ps[6 * NP],
          c3 = ps[7 * NP], c4 = ps[8 * NP];
    float d0 = pd[4 * NP], d1 = pd[5 * NP], d2 = pd[6 * NP],
          d3 = pd[7 * NP], d4 = pd[8 * NP];

    const float* w = tpw + (size_t)le * WNW + u;
    float w0 = w[0],    w1 = w[128],  w2 = w[256],  w3 = w[384],  w4 = w[512];
    float w5 = w[640],  w6 = w[768],  w7 = w[896],  w8 = w[1024], w9 = w[1152];
    float w10 = w[1280];

    float dab = a0 * b0 + a1 * b1 + a2 * b2;
    float dcd = c0 * d0 + c1 * d1 + c2 * d2 + c3 * d3 + c4 * d4;

    float o_s = PW0 * (w0 * ss * sd + w4 * CK1 * dab + w9 * CK2 * dcd);

    float R0 = A0A * a0 * d2 + A2C * (a1 * d1 + a2 * d0 - a0 * d4);
    float R1 = A0B * a1 * d2 + A2C * (a0 * d1 + a2 * d3);
    float R2 = A0A * a2 * d2 + A2C * (a1 * d3 + a0 * d0 + a2 * d4);
    float U0 = A0A * b0 * c2 + A2C * (b1 * c1 + b2 * c0 - b0 * c4);
    float U1 = A0B * b1 * c2 + A2C * (b0 * c1 + b2 * c3);
    float U2 = A0A * b2 * c2 + A2C * (b1 * c3 + b0 * c0 + b2 * c4);
    float o1_0 = PW1 * (CK1 * (w1 * ss * b0 + w3 * a0 * sd) + w6 * R0 + w8 * U0);
    float o1_1 = PW1 * (CK1 * (w1 * ss * b1 + w3 * a1 * sd) + w6 * R1 + w8 * U1);
    float o1_2 = PW1 * (CK1 * (w1 * ss * b2 + w3 * a2 * sd) + w6 * R2 + w8 * U2);

    float S0 = A2C * (a0 * b2 + a2 * b0);
    float S1 = A2C * (a0 * b1 + a1 * b0);
    float S2 = A0A * (a0 * b0 + a2 * b2) + A0B * a1 * b1;
    float S3 = A2C * (a1 * b2 + a2 * b1);
    float S4 = A2C * (a2 * b2 - a0 * b0);
    float V0 = -B2C * (c0 * d2 + c2 * d0) + B3C * (c1 * d3 + c3 * d1);
    float V1 =  B3C * (c0 * d3 + c3 * d0) - B3C * (c1 * d4 + c4 * d1)
              + B1C * (c1 * d2 + c2 * d1);
    float V2 = -B2C * (c0 * d0 + c4 * d4) + B1C * (c1 * d1 + c3 * d3) + B2C * c2 * d2;
    float V3 =  B3C * (c0 * d1 + c1 * d0) + B3C * (c3 * d4 + c4 * d3)
              + B1C * (c2 * d3 + c3 * d2);
    float V4 = -B2C * (c2 * d4 + c4 * d2) - B3C * c1 * d1 + B3C * c3 * d3;
    float o2_0 = PW2 * (CK2 * (w2 * ss * d0 + w7 * c0 * sd) + w5 * S0 + w10 * V0);
    float o2_1 = PW2 * (CK2 * (w2 * ss * d1 + w7 * c1 * sd) + w5 * S1 + w10 * V1);
    float o2_2 = PW2 * (CK2 * (w2 * ss * d2 + w7 * c2 * sd) + w5 * S2 + w10 * V2);
    float o2_3 = PW2 * (CK2 * (w2 * ss * d3 + w7 * c3 * sd) + w5 * S3 + w10 * V3);
    float o2_4 = PW2 * (CK2 * (w2 * ss * d4 + w7 * c4 * sd) + w5 * S4 + w10 * V4);

    size_t FP = (size_t)ec * 128;
    float* po = fij + (size_t)le * 128 + u;
    po[0] = o_s;
    po[FP] = o1_0;     po[2 * FP] = o1_1; po[3 * FP] = o1_2;
    po[4 * FP] = o2_0; po[5 * FP] = o2_1; po[6 * FP] = o2_2;
    po[7 * FP] = o2_3; po[8 * FP] = o2_4;

    // fused f0 = [s, ||v1||, ||v2||]
    float n1 = sqrtf(o1_0 * o1_0 + o1_1 * o1_1 + o1_2 * o1_2);
    float n2 = sqrtf(o2_0 * o2_0 + o2_1 * o2_1 + o2_2 * o2_2
                     + o2_3 * o2_3 + o2_4 * o2_4);
    float* pf = f0 + (size_t)le * 384;
    pf[u] = o_s;
    pf[128 + u] = n1;
    pf[256 + u] = n2;
}

// ============================================================================
extern "C" void kernel_launch(void* const* d_in, const int* in_sizes, int n_in,
                              void* d_out, int out_size, void* d_ws, size_t ws_size,
                              hipStream_t stream)
{
    const float* x         = (const float*)d_in[0];
    const float* edge_attr = (const float*)d_in[1];
    const int*   ei        = (const int*)  d_in[2];
    const float* W_pre0    = (const float*)d_in[3];
    const float* W_pre1    = (const float*)d_in[4];
    const float* W_pre2    = (const float*)d_in[5];
    const float* b_pre0    = (const float*)d_in[6];
    const float* ngpre_W1  = (const float*)d_in[7];
    const float* ngpre_b1  = (const float*)d_in[8];
    const float* ngpre_W2  = (const float*)d_in[9];
    const float* ngpre_b2  = (const float*)d_in[10];
    const float* es_W1     = (const float*)d_in[11];
    const float* es_b1     = (const float*)d_in[12];
    const float* es_W2     = (const float*)d_in[13];
    const float* es_b2     = (const float*)d_in[14];
    const float* er_W1     = (const float*)d_in[15];
    const float* er_b1     = (const float*)d_in[16];
    const float* er_W2     = (const float*)d_in[17];
    const float* er_b2     = (const float*)d_in[18];
    const float* ngpost_W1 = (const float*)d_in[19];
    const float* ngpost_b1 = (const float*)d_in[20];
    const float* ngpost_W2 = (const float*)d_in[21];
    const float* ngpost_b2 = (const float*)d_in[22];
    const float* W_post0   = (const float*)d_in[23];
    const float* W_post1   = (const float*)d_in[24];
    const float* W_post2   = (const float*)d_in[25];
    float* out = (float*)d_out;
    float* ws  = (float*)d_ws;

    // fixed workspace: xp planes (9*N*128), hes, her
    float* xp    = ws;
    float* hes   = ws + (size_t)9 * NNODES * 128;               // 11.52M
    float* her   = hes + (size_t)NEDGES * 128;                  // +6.4M
    float* arena = her + (size_t)NEDGES * 128;                  // 24.32M fixed

    long ws_floats = (long)(ws_size / 4);
    long arena_f = ws_floats - (long)(24320000);
    long ec0 = arena_f / 2944;                                  // tpw+fij+f0 slots
    if (ec0 > NEDGES) ec0 = NEDGES;
    if (ec0 < 1) ec0 = 1;
    int NC = (int)((NEDGES + ec0 - 1) / ec0);
    int Ec = (NEDGES + NC - 1) / NC;

    float* dots = arena;                                        // pre-loop use

    // ---- edge hidden MLPs (full E) ----
    dots_kernel<<<NEDGES, 256, 0, stream>>>(x, ei, dots);

    dim3 gE(1, (NEDGES + 127) / 128);
    gemm128<1, 0, true, false, false><<<gE, 256, 0, stream>>>(
        nullptr, 0, es_W1, 128, nullptr, nullptr, es_b1, nullptr,
        hes, 128, NEDGES, 512, x, ei, dots);
    gemm128<0, 0, true, false, false><<<gE, 256, 0, stream>>>(
        edge_attr, EDIM, er_W1, 128, nullptr, nullptr, er_b1, nullptr,
        her, 128, NEDGES, EDIM, nullptr, nullptr, nullptr);

    // ---- node pre: xp = norm_gate(o3_linear(x))  [plane layout] ----
    dim3 gO3p(1, (NNODES + 127) / 128, 9);
    gemm128<2, 2, false, false, true><<<gO3p, 256, 0, stream>>>(
        x, 0, W_pre0, 128, W_pre1, W_pre2, b_pre0, nullptr,
        xp, 128, NNODES, 128, nullptr, nullptr, nullptr);

    float* f0n = arena;
    float* hb  = f0n + (size_t)NNODES * 384;
    float* gb  = hb + (size_t)NNODES * 384;
    f0_kernel<<<((size_t)NNODES * 384 + 255) / 256, 256, 0, stream>>>(xp, f0n, NNODES);
    dim3 gNGp(3, (NNODES + 127) / 128);
    gemm128<0, 0, true, false, false><<<gNGp, 256, 0, stream>>>(
        f0n, 384, ngpre_W1, 384, nullptr, nullptr, ngpre_b1, nullptr,
        hb, 384, NNODES, 384, nullptr, nullptr, nullptr);
    gemm128<0, 0, false, false, false><<<gNGp, 256, 0, stream>>>(
        hb, 384, ngpre_W2, 384, nullptr, nullptr, ngpre_b2, nullptr,
        gb, 384, NNODES, 384, nullptr, nullptr, nullptr);
    dim3 gGp((NNODES * 128 + 255) / 256, 9);
    gate_kernel<<<gGp, 256, 0, stream>>>(xp, gb, NNODES);

    // ---- edge chunks ----
    for (int c = 0; c < NC; ++c) {
        int e0 = c * Ec;
        int ec = NEDGES - e0; if (ec > Ec) ec = Ec;
        if (ec <= 0) break;

        float* tpwc = arena;
        float* fijc = tpwc + (size_t)Ec * 1408;
        float* f0p  = fijc + (size_t)Ec * 1152;

        // fused: tpw = (hes@es_W2 + es_b2) * (her@er_W2 + er_b2)
        dim3 gW(11, (ec + 127) / 128);
        w2fused<<<gW, 256, 0, stream>>>(
            hes + (size_t)e0 * 128, es_W2, es_b2,
            her + (size_t)e0 * 128, er_W2, er_b2,
            tpwc, ec);

        // TP + fused f0
        tp_kernel<<<(ec + 1) / 2, 256, 0, stream>>>(xp, ei, tpwc, fijc, f0p, e0, ec);

        // tpw dead: reuse its slot for h1/g (2*384 = 768 <= 1408)
        float* h1p = tpwc;
        float* gp  = tpwc + (size_t)Ec * 384;
        dim3 gNG(3, (ec + 127) / 128);
        gemm128<0, 0, true, false, false><<<gNG, 256, 0, stream>>>(
            f0p, 384, ngpost_W1, 384, nullptr, nullptr, ngpost_b1, nullptr,
            h1p, 384, ec, 384, nullptr, nullptr, nullptr);
        gemm128<0, 0, false, false, false><<<gNG, 256, 0, stream>>>(
            h1p, 384, ngpost_W2, 384, nullptr, nullptr, ngpost_b2, nullptr,
            gp, 384, ec, 384, nullptr, nullptr, nullptr);

        // o3-post with gate fused into A staging (AMODE 4)
        dim3 gO3q(1, (ec + 127) / 128, 9);
        gemm128<4, 1, false, false, true><<<gO3q, 256, 0, stream>>>(
            fijc, 128, W_post0, 128, W_post1, W_post2, nullptr, nullptr,
            out + (size_t)e0 * ND, 128, ec, 128, gp, nullptr, nullptr);
    }
}

// Round 2
// 1730.508 us; speedup vs baseline: 1.5651x; 1.4409x over previous
//
#include <hip/hip_runtime.h>
#include <math.h>

#define NNODES 10000
#define NEDGES 50000
#define ND 1152
#define MUL 128
#define WNW 1408
#define EDIM 20

#define CK1 0.5773502691896258f
#define CK2 0.4472135954999579f
#define A2C 0.31622776601683794f
#define A0A (-0.18257418583505536f)
#define A0B 0.3651483716701107f
#define B1C 0.11952286093343936f
#define B2C 0.23904572186687873f
#define B3C 0.20701966780270626f
#define PW0 0.5773502691896258f
#define PW1 0.8660254037844386f
#define PW2 1.1180339887498949f
#define INV128 0.08838834764831845f

__device__ __forceinline__ float silu_f(float v) { return v / (1.f + expf(-v)); }

typedef short bfrag __attribute__((ext_vector_type(8)));   // 8 bf16 (4 VGPR)
typedef float f32x4 __attribute__((ext_vector_type(4)));

__device__ __forceinline__ ushort f2bf(float f) {          // RNE fp32->bf16
    uint u = __float_as_uint(f);
    u += 0x7fffu + ((u >> 16) & 1u);
    return (ushort)(u >> 16);
}
__device__ __forceinline__ float bf2f(ushort h) {
    return __uint_as_float(((uint)h) << 16);
}

// ============================================================================
// Split-bf16 MFMA GEMM: C = A @ B (+bias), A fp32 split on the fly,
// B pre-split/transposed bf16 hi/lo ([n][k] layout).
// 128x128 tile, 256 thr = 4 waves (2x2 of 64x64), 16x16x32 bf16 MFMA,
// 3 products per pair (hi*hi + hi*lo + lo*hi).
// DUAL: two GEMMs (A1@B1, A2@B2), epilogue C = (r1+b1)*(r2+b2)  [w2fused].
// else: C = silu?(r1+b1).
// K multiple of 32; N = gridDim.x*128 exactly; M guarded.
// ============================================================================
#define LSTR 40   // LDS row stride in bf16 (80 B = 20-bank step -> <=2-way)

template<bool DUAL, bool SILU>
__global__ __launch_bounds__(256) void gemmbf(
    const float* __restrict__ A1, int lda,
    const ushort* __restrict__ B1H, const ushort* __restrict__ B1L,
    const float* __restrict__ b1,
    const float* __restrict__ A2,
    const ushort* __restrict__ B2H, const ushort* __restrict__ B2L,
    const float* __restrict__ b2,
    float* __restrict__ C, int ldc, int M, int K)
{
    __shared__ __align__(16) ushort Ah[128 * LSTR];
    __shared__ __align__(16) ushort Al[128 * LSTR];
    __shared__ __align__(16) ushort Bh[128 * LSTR];
    __shared__ __align__(16) ushort Bl[128 * LSTR];

    const int tid = threadIdx.x;
    const int l   = tid & 63;
    const int wid = tid >> 6;
    const int wr  = (wid >> 1) << 6;       // wave row offset (0/64)
    const int wc  = (wid & 1) << 6;        // wave col offset (0/64)
    const int rowBase = blockIdx.y << 7;
    const int n0      = blockIdx.x << 7;

    const int sRow = tid >> 1;             // A staging: row 0..127
    const int sK   = (tid & 1) << 4;       // 0/16 (floats)
    const int bN   = tid & 127;            // B staging: n 0..127
    const int bK   = (tid >> 7) << 4;      // 0/16 (bf16)

    const int frow = l & 15;               // fragment row/col within 16
    const int fk   = (l >> 4) << 3;        // fragment k offset (0,8,16,24)

    f32x4 acc0[4][4], acc1[4][4];
#pragma unroll
    for (int m = 0; m < 4; ++m)
#pragma unroll
        for (int n = 0; n < 4; ++n) {
            acc0[m][n] = f32x4{0.f, 0.f, 0.f, 0.f};
            if constexpr (DUAL) acc1[m][n] = f32x4{0.f, 0.f, 0.f, 0.f};
        }

#pragma unroll
    for (int ph = 0; ph < (DUAL ? 2 : 1); ++ph) {
        const float*  A  = (DUAL && ph) ? A2  : A1;
        const ushort* BH = (DUAL && ph) ? B2H : B1H;
        const ushort* BL = (DUAL && ph) ? B2L : B1L;
        for (int k0 = 0; k0 < K; k0 += 32) {
            // ---- stage A: fp32 -> split bf16 hi/lo into LDS ----
            float f[16];
            int grow = rowBase + sRow;
            if (grow < M) {
                const float4* p = (const float4*)&A[(size_t)grow * lda + k0 + sK];
#pragma unroll
                for (int j = 0; j < 4; ++j) {
                    float4 v = p[j];
                    f[j * 4 + 0] = v.x; f[j * 4 + 1] = v.y;
                    f[j * 4 + 2] = v.z; f[j * 4 + 3] = v.w;
                }
            } else {
#pragma unroll
                for (int j = 0; j < 16; ++j) f[j] = 0.f;
            }
            {
                int base = sRow * LSTR + sK;
#pragma unroll
                for (int j = 0; j < 4; ++j) {
                    ushort4 hv, lv;
                    hv.x = f2bf(f[j * 4 + 0]); lv.x = f2bf(f[j * 4 + 0] - bf2f(hv.x));
                    hv.y = f2bf(f[j * 4 + 1]); lv.y = f2bf(f[j * 4 + 1] - bf2f(hv.y));
                    hv.z = f2bf(f[j * 4 + 2]); lv.z = f2bf(f[j * 4 + 2] - bf2f(hv.z));
                    hv.w = f2bf(f[j * 4 + 3]); lv.w = f2bf(f[j * 4 + 3] - bf2f(hv.w));
                    *(ushort4*)&Ah[base + j * 4] = hv;
                    *(ushort4*)&Al[base + j * 4] = lv;
                }
            }
            // ---- stage B: pre-split bf16 copy (16 bf16/thread/part) ----
            {
                size_t go = (size_t)(n0 + bN) * K + k0 + bK;
                uint4 h0 = *(const uint4*)&BH[go];
                uint4 h1 = *(const uint4*)&BH[go + 8];
                uint4 l0 = *(const uint4*)&BL[go];
                uint4 l1 = *(const uint4*)&BL[go + 8];
                int bb = bN * LSTR + bK;
                *(uint4*)&Bh[bb]     = h0;
                *(uint4*)&Bh[bb + 8] = h1;
                *(uint4*)&Bl[bb]     = l0;
                *(uint4*)&Bl[bb + 8] = l1;
            }
            __syncthreads();
            // ---- fragments + MFMA (3 split products) ----
            bfrag bhF[4], blF[4];
#pragma unroll
            for (int n = 0; n < 4; ++n) {
                int r = (wc + n * 16 + frow) * LSTR + fk;
                bhF[n] = *(const bfrag*)&Bh[r];
                blF[n] = *(const bfrag*)&Bl[r];
            }
#pragma unroll
            for (int m = 0; m < 4; ++m) {
                int r = (wr + m * 16 + frow) * LSTR + fk;
                bfrag ah = *(const bfrag*)&Ah[r];
                bfrag al = *(const bfrag*)&Al[r];
#pragma unroll
                for (int n = 0; n < 4; ++n) {
                    f32x4 a = (DUAL && ph) ? acc1[m][n] : acc0[m][n];
                    a = __builtin_amdgcn_mfma_f32_16x16x32_bf16(ah, bhF[n], a, 0, 0, 0);
                    a = __builtin_amdgcn_mfma_f32_16x16x32_bf16(ah, blF[n], a, 0, 0, 0);
                    a = __builtin_amdgcn_mfma_f32_16x16x32_bf16(al, bhF[n], a, 0, 0, 0);
                    if (DUAL && ph) acc1[m][n] = a; else acc0[m][n] = a;
                }
            }
            __syncthreads();
        }
    }

    // ---- epilogue ----
#pragma unroll
    for (int n = 0; n < 4; ++n) {
        int col = n0 + wc + n * 16 + frow;
        float bb1 = b1[col];
        float bb2 = DUAL ? b2[col] : 0.f;
#pragma unroll
        for (int m = 0; m < 4; ++m) {
            int row0 = rowBase + wr + m * 16 + ((l >> 4) << 2);
#pragma unroll
            for (int q = 0; q < 4; ++q) {
                int row = row0 + q;
                if (row >= M) continue;
                float v;
                if constexpr (DUAL) {
                    v = (acc0[m][n][q] + bb1) * (acc1[m][n][q] + bb2);
                } else {
                    v = acc0[m][n][q] + bb1;
                    if constexpr (SILU) v = silu_f(v);
                }
                C[(size_t)row * ldc + col] = v;
            }
        }
    }
}

// ============================================================================
// One-time weight split+transpose: W[K][N] fp32 -> H/L [N][K] bf16.
// grid.y selects matrix; out is one packed ushort arena.
// ============================================================================
__global__ void wsplit_kernel(
    const float* __restrict__ W0, const float* __restrict__ W1,
    const float* __restrict__ W2, const float* __restrict__ W3,
    const float* __restrict__ W4, const float* __restrict__ W5,
    ushort* __restrict__ out)
{
    int m = blockIdx.y;
    const float* W; int K, N; size_t off;
    switch (m) {
        case 0:  W = W0; K = 128; N = 1408; off = 0;        break;
        case 1:  W = W1; K = 128; N = 1408; off = 360448;   break;
        case 2:  W = W2; K = 384; N = 384;  off = 720896;   break;
        case 3:  W = W3; K = 384; N = 384;  off = 1015808;  break;
        case 4:  W = W4; K = 384; N = 384;  off = 1310720;  break;
        default: W = W5; K = 384; N = 384;  off = 1605632;  break;
    }
    int idx = blockIdx.x * 256 + threadIdx.x;
    if (idx >= K * N) return;
    int k = idx / N, n = idx - k * N;
    float v = W[idx];
    ushort h  = f2bf(v);
    ushort lo = f2bf(v - bf2f(h));
    size_t KN = (size_t)K * N;
    out[off + (size_t)n * K + k]      = h;
    out[off + KN + (size_t)n * K + k] = lo;
}

// ============================================================================
// 128x128-tile fp32 GEMM (kept for es1 / er1 / o3 pre / o3 post).
// ============================================================================
template<int AMODE, int OMODE, bool SILU, bool FMUL, bool O3S>
__global__ __launch_bounds__(256) void gemm128(
    const float* __restrict__ A, int lda,
    const float* __restrict__ B, int ldb,
    const float* __restrict__ W1p, const float* __restrict__ W2p,
    const float* __restrict__ bias, const float* __restrict__ M2,
    float* __restrict__ C, int ldc, int M, int K,
    const float* __restrict__ xg, const int* __restrict__ ei,
    const float* __restrict__ dots)
{
    __shared__ float Ast[32][132];
    __shared__ float Bs[32][132];

    const int tid = threadIdx.x;
    const int tx = tid & 15, ty = tid >> 4;
    const int rowBase = blockIdx.y << 7;
    const int n0 = blockIdx.x << 7;
    const int z = blockIdx.z;

    int off = 0, stride = 1;
    if constexpr (AMODE == 2 || AMODE == 3 || AMODE == 4 || OMODE == 1 || O3S) {
        if (z == 0)      { off = 0;             stride = 1; }
        else if (z < 4)  { off = 128 + (z - 1); stride = 3; }
        else             { off = 512 + (z - 4); stride = 5; }
    }
    const float* Bz = B;
    if constexpr (AMODE >= 2) {   // o3 weight select by l
        if (z >= 1 && z < 4) Bz = W1p;
        else if (z >= 4)     Bz = W2p;
    }
    const float* Ab = A;
    if constexpr (AMODE == 3 || AMODE == 4) Ab = A + (size_t)z * M * lda;
    float* Cb = C;
    if constexpr (OMODE == 2) Cb = C + (size_t)z * M * ldc;

    float acc[2][2][4][4] = {};

    for (int k0 = 0; k0 < K; k0 += 32) {
        // ---- stage A (transposed into LDS) ----
#pragma unroll
        for (int i = 0; i < 4; ++i) {
            int f4 = tid + (i << 8);          // 0..1023
            int row = f4 >> 3;                // 0..127
            int kq  = (f4 & 7) << 2;          // 0,4,..,28
            int grow = rowBase + row, gk = k0 + kq;
            float4 v = make_float4(0.f, 0.f, 0.f, 0.f);
            if (grow < M) {
                if constexpr (AMODE == 0 || AMODE == 3) {
                    if (gk + 4 <= K) {
                        v = *(const float4*)&Ab[(size_t)grow * lda + gk];
                    } else {
                        float t[4] = {0.f, 0.f, 0.f, 0.f};
#pragma unroll
                        for (int j = 0; j < 4; ++j)
                            if (gk + j < K) t[j] = Ab[(size_t)grow * lda + gk + j];
                        v = make_float4(t[0], t[1], t[2], t[3]);
                    }
                } else if constexpr (AMODE == 1) {
                    if (gk < 128)
                        v = *(const float4*)&xg[(size_t)ei[grow] * ND + gk];
                    else if (gk < 256)
                        v = *(const float4*)&xg[(size_t)ei[NEDGES + grow] * ND + (gk - 128)];
                    else
                        v = *(const float4*)&dots[(size_t)grow * 256 + (gk - 256)];
                } else if constexpr (AMODE == 2) {  // strided component from interleaved rows
                    const float* p = &Ab[(size_t)grow * ND + off];
                    v.x = p[(gk + 0) * stride];
                    v.y = p[(gk + 1) * stride];
                    v.z = p[(gk + 2) * stride];
                    v.w = p[(gk + 3) * stride];
                } else {  // AMODE 4: gated plane read
                    int gsel = (z == 0) ? 0 : (z < 4 ? 128 : 256);
                    float4 vg = *(const float4*)&xg[(size_t)grow * 384 + gsel + gk];
                    if (z == 0) {
                        v = vg;
                    } else {
                        float4 vf = *(const float4*)&Ab[(size_t)grow * lda + gk];
                        v = make_float4(vf.x * vg.x, vf.y * vg.y,
                                        vf.z * vg.z, vf.w * vg.w);
                    }
                }
            }
            Ast[kq + 0][row] = v.x;
            Ast[kq + 1][row] = v.y;
            Ast[kq + 2][row] = v.z;
            Ast[kq + 3][row] = v.w;
        }
        // ---- stage B ----
#pragma unroll
        for (int i = 0; i < 4; ++i) {
            int f4 = tid + (i << 8);
            int bk = f4 >> 5;                 // 0..31
            int nq = (f4 & 31) << 2;          // 0..124
            float4 v = make_float4(0.f, 0.f, 0.f, 0.f);
            if (k0 + bk < K)
                v = *(const float4*)&Bz[(size_t)(k0 + bk) * ldb + n0 + nq];
            *(float4*)&Bs[bk][nq] = v;
        }
        __syncthreads();
#pragma unroll
        for (int kk = 0; kk < 32; ++kk) {
            float4 a0 = *(const float4*)&Ast[kk][(ty << 2)];
            float4 a1 = *(const float4*)&Ast[kk][64 + (ty << 2)];
            float4 b0 = *(const float4*)&Bs[kk][(tx << 2)];
            float4 b1 = *(const float4*)&Bs[kk][64 + (tx << 2)];
            float ar[2][4] = {{a0.x, a0.y, a0.z, a0.w}, {a1.x, a1.y, a1.z, a1.w}};
            float br[2][4] = {{b0.x, b0.y, b0.z, b0.w}, {b1.x, b1.y, b1.z, b1.w}};
#pragma unroll
            for (int h = 0; h < 2; ++h)
#pragma unroll
                for (int g = 0; g < 2; ++g)
#pragma unroll
                    for (int ii = 0; ii < 4; ++ii)
#pragma unroll
                        for (int jj = 0; jj < 4; ++jj)
                            acc[h][g][ii][jj] = fmaf(ar[h][ii], br[g][jj], acc[h][g][ii][jj]);
        }
        __syncthreads();
    }

    // ---- epilogue ----
#pragma unroll
    for (int h = 0; h < 2; ++h) {
#pragma unroll
        for (int ii = 0; ii < 4; ++ii) {
            int row = rowBase + (h << 6) + (ty << 2) + ii;
            if (row >= M) continue;
#pragma unroll
            for (int g = 0; g < 2; ++g) {
                int colq = n0 + (g << 6) + (tx << 2);
                float o[4];
#pragma unroll
                for (int jj = 0; jj < 4; ++jj) {
                    float v = acc[h][g][ii][jj];
                    int col = colq + jj;
                    if constexpr (O3S) {
                        v *= INV128;
                        if (bias && z == 0) v += bias[col];
                    } else {
                        if (bias) v += bias[col];
                    }
                    if constexpr (SILU) v = silu_f(v);
                    if constexpr (FMUL) v *= M2[(size_t)row * ldc + col];
                    o[jj] = v;
                }
                if constexpr (OMODE == 1) {
                    float* p = &Cb[(size_t)row * ND + off];
#pragma unroll
                    for (int jj = 0; jj < 4; ++jj) p[(colq + jj) * stride] = o[jj];
                } else {
                    *(float4*)&Cb[(size_t)row * ldc + colq] =
                        make_float4(o[0], o[1], o[2], o[3]);
                }
            }
        }
    }
}

// ============================================================================
// dots for s0 (reads interleaved input x)
// ============================================================================
__global__ void dots_kernel(const float* __restrict__ x, const int* __restrict__ ei,
                            float* __restrict__ dots)
{
    int idx = blockIdx.x * 256 + threadIdx.x;
    int e = idx >> 8, t = idx & 255;
    if (e >= NEDGES) return;
    const float* ps = x + (size_t)ei[e] * ND;
    const float* pd = x + (size_t)ei[NEDGES + e] * ND;
    float v;
    if (t < 128) {
        int u = 128 + t * 3;
        v = (ps[u] * pd[u] + ps[u + 1] * pd[u + 1] + ps[u + 2] * pd[u + 2]) * CK1;
    } else {
        int u = 512 + (t - 128) * 5;
        v = (ps[u] * pd[u] + ps[u + 1] * pd[u + 1] + ps[u + 2] * pd[u + 2]
             + ps[u + 3] * pd[u + 3] + ps[u + 4] * pd[u + 4]) * CK2;
    }
    dots[idx] = v;
}

// ============================================================================
// f0 = [s, ||v1||_c, ||v2||_c] from PLANE layout (node side)
// ============================================================================
__global__ void f0_kernel(const float* __restrict__ in, float* __restrict__ f0, int M)
{
    int idx = blockIdx.x * 256 + threadIdx.x;
    int r = idx / 384, t = idx - r * 384;
    if (r >= M) return;
    size_t P = (size_t)M * 128;
    const float* p = in + (size_t)r * 128;
    float v;
    if (t < 128) v = p[t];
    else if (t < 256) {
        int u = t - 128;
        float x1 = p[P + u], x2 = p[2 * P + u], x3 = p[3 * P + u];
        v = sqrtf(x1 * x1 + x2 * x2 + x3 * x3);
    } else {
        int u = t - 256;
        float x1 = p[4 * P + u], x2 = p[5 * P + u], x3 = p[6 * P + u],
              x4 = p[7 * P + u], x5 = p[8 * P + u];
        v = sqrtf(x1 * x1 + x2 * x2 + x3 * x3 + x4 * x4 + x5 * x5);
    }
    f0[(size_t)r * 384 + t] = v;
}

// gate in place on PLANE layout (node side). grid: (ceil(M*128/256), 9)
__global__ void gate_kernel(float* __restrict__ xp, const float* __restrict__ g, int M)
{
    int t = blockIdx.x * 256 + threadIdx.x;
    if (t >= M * 128) return;
    int z = blockIdx.y;
    int r = t >> 7, u = t & 127;
    float* p = xp + (size_t)z * M * 128 + t;
    const float* gr = g + (size_t)r * 384;
    if (z == 0)      *p = gr[u];
    else if (z < 4)  *p *= gr[128 + u];
    else             *p *= gr[256 + u];
}

// ============================================================================
// Wigner TP, plane layout in (xp) and out (fij). 2 edges per block.
// Emits f0 = [o_s, ||o1||, ||o2||] directly.
// ============================================================================
__global__ __launch_bounds__(256) void tp_kernel(
    const float* __restrict__ xp, const int* __restrict__ ei,
    const float* __restrict__ tpw, float* __restrict__ fij,
    float* __restrict__ f0, int e0, int ec)
{
    int le = blockIdx.x * 2 + (threadIdx.x >> 7);
    int u = threadIdx.x & 127;
    if (le >= ec) return;
    int e = e0 + le;
    const size_t NP = (size_t)NNODES * 128;
    const float* ps = xp + (size_t)ei[e] * 128 + u;
    const float* pd = xp + (size_t)ei[NEDGES + e] * 128 + u;

    float ss = ps[0], sd = pd[0];
    float a0 = ps[NP],     a1 = ps[2 * NP], a2 = ps[3 * NP];
    float b0 = pd[NP],     b1 = pd[2 * NP], b2 = pd[3 * NP];
    float c0 = ps[4 * NP], c1 = ps[5 * NP], c2 = ps[6 * NP],
          c3 = ps[7 * NP], c4 = ps[8 * NP];
    float d0 = pd[4 * NP], d1 = pd[5 * NP], d2 = pd[6 * NP],
          d3 = pd[7 * NP], d4 = pd[8 * NP];

    const float* w = tpw + (size_t)le * WNW + u;
    float w0 = w[0],    w1 = w[128],  w2 = w[256],  w3 = w[384],  w4 = w[512];
    float w5 = w[640],  w6 = w[768],  w7 = w[896],  w8 = w[1024], w9 = w[1152];
    float w10 = w[1280];

    float dab = a0 * b0 + a1 * b1 + a2 * b2;
    float dcd = c0 * d0 + c1 * d1 + c2 * d2 + c3 * d3 + c4 * d4;

    float o_s = PW0 * (w0 * ss * sd + w4 * CK1 * dab + w9 * CK2 * dcd);

    float R0 = A0A * a0 * d2 + A2C * (a1 * d1 + a2 * d0 - a0 * d4);
    float R1 = A0B * a1 * d2 + A2C * (a0 * d1 + a2 * d3);
    float R2 = A0A * a2 * d2 + A2C * (a1 * d3 + a0 * d0 + a2 * d4);
    float U0 = A0A * b0 * c2 + A2C * (b1 * c1 + b2 * c0 - b0 * c4);
    float U1 = A0B * b1 * c2 + A2C * (b0 * c1 + b2 * c3);
    float U2 = A0A * b2 * c2 + A2C * (b1 * c3 + b0 * c0 + b2 * c4);
    float o1_0 = PW1 * (CK1 * (w1 * ss * b0 + w3 * a0 * sd) + w6 * R0 + w8 * U0);
    float o1_1 = PW1 * (CK1 * (w1 * ss * b1 + w3 * a1 * sd) + w6 * R1 + w8 * U1);
    float o1_2 = PW1 * (CK1 * (w1 * ss * b2 + w3 * a2 * sd) + w6 * R2 + w8 * U2);

    float S0 = A2C * (a0 * b2 + a2 * b0);
    float S1 = A2C * (a0 * b1 + a1 * b0);
    float S2 = A0A * (a0 * b0 + a2 * b2) + A0B * a1 * b1;
    float S3 = A2C * (a1 * b2 + a2 * b1);
    float S4 = A2C * (a2 * b2 - a0 * b0);
    float V0 = -B2C * (c0 * d2 + c2 * d0) + B3C * (c1 * d3 + c3 * d1);
    float V1 =  B3C * (c0 * d3 + c3 * d0) - B3C * (c1 * d4 + c4 * d1)
              + B1C * (c1 * d2 + c2 * d1);
    float V2 = -B2C * (c0 * d0 + c4 * d4) + B1C * (c1 * d1 + c3 * d3) + B2C * c2 * d2;
    float V3 =  B3C * (c0 * d1 + c1 * d0) + B3C * (c3 * d4 + c4 * d3)
              + B1C * (c2 * d3 + c3 * d2);
    float V4 = -B2C * (c2 * d4 + c4 * d2) - B3C * c1 * d1 + B3C * c3 * d3;
    float o2_0 = PW2 * (CK2 * (w2 * ss * d0 + w7 * c0 * sd) + w5 * S0 + w10 * V0);
    float o2_1 = PW2 * (CK2 * (w2 * ss * d1 + w7 * c1 * sd) + w5 * S1 + w10 * V1);
    float o2_2 = PW2 * (CK2 * (w2 * ss * d2 + w7 * c2 * sd) + w5 * S2 + w10 * V2);
    float o2_3 = PW2 * (CK2 * (w2 * ss * d3 + w7 * c3 * sd) + w5 * S3 + w10 * V3);
    float o2_4 = PW2 * (CK2 * (w2 * ss * d4 + w7 * c4 * sd) + w5 * S4 + w10 * V4);

    size_t FP = (size_t)ec * 128;
    float* po = fij + (size_t)le * 128 + u;
    po[0] = o_s;
    po[FP] = o1_0;     po[2 * FP] = o1_1; po[3 * FP] = o1_2;
    po[4 * FP] = o2_0; po[5 * FP] = o2_1; po[6 * FP] = o2_2;
    po[7 * FP] = o2_3; po[8 * FP] = o2_4;

    // fused f0 = [s, ||v1||, ||v2||]
    float n1 = sqrtf(o1_0 * o1_0 + o1_1 * o1_1 + o1_2 * o1_2);
    float n2 = sqrtf(o2_0 * o2_0 + o2_1 * o2_1 + o2_2 * o2_2
                     + o2_3 * o2_3 + o2_4 * o2_4);
    float* pf = f0 + (size_t)le * 384;
    pf[u] = o_s;
    pf[128 + u] = n1;
    pf[256 + u] = n2;
}

// ============================================================================
extern "C" void kernel_launch(void* const* d_in, const int* in_sizes, int n_in,
                              void* d_out, int out_size, void* d_ws, size_t ws_size,
                              hipStream_t stream)
{
    const float* x         = (const float*)d_in[0];
    const float* edge_attr = (const float*)d_in[1];
    const int*   ei        = (const int*)  d_in[2];
    const float* W_pre0    = (const float*)d_in[3];
    const float* W_pre1    = (const float*)d_in[4];
    const float* W_pre2    = (const float*)d_in[5];
    const float* b_pre0    = (const float*)d_in[6];
    const float* ngpre_W1  = (const float*)d_in[7];
    const float* ngpre_b1  = (const float*)d_in[8];
    const float* ngpre_W2  = (const float*)d_in[9];
    const float* ngpre_b2  = (const float*)d_in[10];
    const float* es_W1     = (const float*)d_in[11];
    const float* es_b1     = (const float*)d_in[12];
    const float* es_W2     = (const float*)d_in[13];
    const float* es_b2     = (const float*)d_in[14];
    const float* er_W1     = (const float*)d_in[15];
    const float* er_b1     = (const float*)d_in[16];
    const float* er_W2     = (const float*)d_in[17];
    const float* er_b2     = (const float*)d_in[18];
    const float* ngpost_W1 = (const float*)d_in[19];
    const float* ngpost_b1 = (const float*)d_in[20];
    const float* ngpost_W2 = (const float*)d_in[21];
    const float* ngpost_b2 = (const float*)d_in[22];
    const float* W_post0   = (const float*)d_in[23];
    const float* W_post1   = (const float*)d_in[24];
    const float* W_post2   = (const float*)d_in[25];
    float* out = (float*)d_out;
    float* ws  = (float*)d_ws;

    // fixed workspace: xp planes (9*N*128), hes, her, bf16 weight splits
    float* xp    = ws;
    float* hes   = ws + (size_t)9 * NNODES * 128;               // 11.52M
    float* her   = hes + (size_t)NEDGES * 128;                  // +6.4M
    ushort* wsp  = (ushort*)(her + (size_t)NEDGES * 128);       // 1.9M ushorts
    const ushort* esW2tH   = wsp;
    const ushort* esW2tL   = wsp + 180224;
    const ushort* erW2tH   = wsp + 360448;
    const ushort* erW2tL   = wsp + 540672;
    const ushort* preW1H   = wsp + 720896;
    const ushort* preW1L   = wsp + 868352;
    const ushort* preW2H   = wsp + 1015808;
    const ushort* preW2L   = wsp + 1163264;
    const ushort* postW1H  = wsp + 1310720;
    const ushort* postW1L  = wsp + 1458176;
    const ushort* postW2H  = wsp + 1605632;
    const ushort* postW2L  = wsp + 1753088;
    float* arena = her + (size_t)NEDGES * 128 + 950272;         // 25.27M fixed

    long ws_floats = (long)(ws_size / 4);
    long arena_f = ws_floats - 25270272L;
    long ec0 = arena_f / 2944;                                  // tpw+fij+f0 slots
    if (ec0 > NEDGES) ec0 = NEDGES;
    if (ec0 < 1) ec0 = 1;
    int NC = (int)((NEDGES + ec0 - 1) / ec0);
    int Ec = (NEDGES + NC - 1) / NC;

    float* dots = arena;                                        // pre-loop use

    // ---- one-time weight split/transpose ----
    wsplit_kernel<<<dim3(704, 6), 256, 0, stream>>>(
        es_W2, er_W2, ngpre_W1, ngpre_W2, ngpost_W1, ngpost_W2, wsp);

    // ---- edge hidden MLPs (full E) ----
    dots_kernel<<<NEDGES, 256, 0, stream>>>(x, ei, dots);

    dim3 gE(1, (NEDGES + 127) / 128);
    gemm128<1, 0, true, false, false><<<gE, 256, 0, stream>>>(
        nullptr, 0, es_W1, 128, nullptr, nullptr, es_b1, nullptr,
        hes, 128, NEDGES, 512, x, ei, dots);
    gemm128<0, 0, true, false, false><<<gE, 256, 0, stream>>>(
        edge_attr, EDIM, er_W1, 128, nullptr, nullptr, er_b1, nullptr,
        her, 128, NEDGES, EDIM, nullptr, nullptr, nullptr);

    // ---- node pre: xp = norm_gate(o3_linear(x))  [plane layout] ----
    dim3 gO3p(1, (NNODES + 127) / 128, 9);
    gemm128<2, 2, false, false, true><<<gO3p, 256, 0, stream>>>(
        x, 0, W_pre0, 128, W_pre1, W_pre2, b_pre0, nullptr,
        xp, 128, NNODES, 128, nullptr, nullptr, nullptr);

    float* f0n = arena;
    float* hb  = f0n + (size_t)NNODES * 384;
    float* gb  = hb + (size_t)NNODES * 384;
    f0_kernel<<<((size_t)NNODES * 384 + 255) / 256, 256, 0, stream>>>(xp, f0n, NNODES);
    dim3 gNGp(3, (NNODES + 127) / 128);
    gemmbf<false, true><<<gNGp, 256, 0, stream>>>(
        f0n, 384, preW1H, preW1L, ngpre_b1,
        nullptr, nullptr, nullptr, nullptr,
        hb, 384, NNODES, 384);
    gemmbf<false, false><<<gNGp, 256, 0, stream>>>(
        hb, 384, preW2H, preW2L, ngpre_b2,
        nullptr, nullptr, nullptr, nullptr,
        gb, 384, NNODES, 384);
    dim3 gGp((NNODES * 128 + 255) / 256, 9);
    gate_kernel<<<gGp, 256, 0, stream>>>(xp, gb, NNODES);

    // ---- edge chunks ----
    for (int c = 0; c < NC; ++c) {
        int e0 = c * Ec;
        int ec = NEDGES - e0; if (ec > Ec) ec = Ec;
        if (ec <= 0) break;

        float* tpwc = arena;
        float* fijc = tpwc + (size_t)Ec * 1408;
        float* f0p  = fijc + (size_t)Ec * 1152;

        // fused split-bf16 MFMA: tpw = (hes@es_W2 + es_b2) * (her@er_W2 + er_b2)
        dim3 gW(11, (ec + 127) / 128);
        gemmbf<true, false><<<gW, 256, 0, stream>>>(
            hes + (size_t)e0 * 128, 128, esW2tH, esW2tL, es_b2,
            her + (size_t)e0 * 128, erW2tH, erW2tL, er_b2,
            tpwc, WNW, ec, 128);

        // TP + fused f0
        tp_kernel<<<(ec + 1) / 2, 256, 0, stream>>>(xp, ei, tpwc, fijc, f0p, e0, ec);

        // tpw dead: reuse its slot for h1/g (2*384 = 768 <= 1408)
        float* h1p = tpwc;
        float* gp  = tpwc + (size_t)Ec * 384;
        dim3 gNG(3, (ec + 127) / 128);
        gemmbf<false, true><<<gNG, 256, 0, stream>>>(
            f0p, 384, postW1H, postW1L, ngpost_b1,
            nullptr, nullptr, nullptr, nullptr,
            h1p, 384, ec, 384);
        gemmbf<false, false><<<gNG, 256, 0, stream>>>(
            h1p, 384, postW2H, postW2L, ngpost_b2,
            nullptr, nullptr, nullptr, nullptr,
            gp, 384, ec, 384);

        // o3-post with gate fused into A staging (AMODE 4)
        dim3 gO3q(1, (ec + 127) / 128, 9);
        gemm128<4, 1, false, false, true><<<gO3q, 256, 0, stream>>>(
            fijc, 128, W_post0, 128, W_post1, W_post2, nullptr, nullptr,
            out + (size_t)e0 * ND, 128, ec, 128, gp, nullptr, nullptr);
    }
}

// Round 3
// 1413.806 us; speedup vs baseline: 1.9157x; 1.2240x over previous
//
#include <hip/hip_runtime.h>
#include <math.h>

#define NNODES 10000
#define NEDGES 50000
#define ND 1152
#define MUL 128
#define WNW 1408
#define EDIM 20

#define CK1 0.5773502691896258f
#define CK2 0.4472135954999579f
#define A2C 0.31622776601683794f
#define A0A (-0.18257418583505536f)
#define A0B 0.3651483716701107f
#define B1C 0.11952286093343936f
#define B2C 0.23904572186687873f
#define B3C 0.20701966780270626f
#define PW0 0.5773502691896258f
#define PW1 0.8660254037844386f
#define PW2 1.1180339887498949f
#define INV128 0.08838834764831845f

__device__ __forceinline__ float silu_f(float v) { return v / (1.f + expf(-v)); }

typedef short bfrag __attribute__((ext_vector_type(8)));   // 8 bf16 (4 VGPR)
typedef float f32x4 __attribute__((ext_vector_type(4)));

__device__ __forceinline__ ushort f2bf(float f) {          // RNE fp32->bf16
    uint u = __float_as_uint(f);
    u += 0x7fffu + ((u >> 16) & 1u);
    return (ushort)(u >> 16);
}
__device__ __forceinline__ float bf2f(ushort h) {
    return __uint_as_float(((uint)h) << 16);
}

#define LSTR 40   // LDS row stride in bf16 (80 B = 20-bank step -> <=2-way)

// ============================================================================
// Split-bf16 MFMA GEMM: C = A @ B (+bias), A fp32 split on the fly,
// B pre-split/transposed bf16 hi/lo ([n][k] layout).
// 128x128 tile, 256 thr = 4 waves (2x2 of 64x64), 16x16x32 bf16 MFMA,
// 3 products per pair (hi*hi + hi*lo + lo*hi).
// DUAL: two GEMMs (A1@B1, A2@B2), epilogue C = (r1+b1)*(r2+b2)  [w2fused].
// else: C = silu?(r1+b1).
// ============================================================================
template<bool DUAL, bool SILU>
__global__ __launch_bounds__(256) void gemmbf(
    const float* __restrict__ A1, int lda,
    const ushort* __restrict__ B1H, const ushort* __restrict__ B1L,
    const float* __restrict__ b1,
    const float* __restrict__ A2,
    const ushort* __restrict__ B2H, const ushort* __restrict__ B2L,
    const float* __restrict__ b2,
    float* __restrict__ C, int ldc, int M, int K)
{
    __shared__ __align__(16) ushort Ah[128 * LSTR];
    __shared__ __align__(16) ushort Al[128 * LSTR];
    __shared__ __align__(16) ushort Bh[128 * LSTR];
    __shared__ __align__(16) ushort Bl[128 * LSTR];

    const int tid = threadIdx.x;
    const int l   = tid & 63;
    const int wid = tid >> 6;
    const int wr  = (wid >> 1) << 6;       // wave row offset (0/64)
    const int wc  = (wid & 1) << 6;        // wave col offset (0/64)
    const int rowBase = blockIdx.y << 7;
    const int n0      = blockIdx.x << 7;

    const int sRow = tid >> 1;             // A staging: row 0..127
    const int sK   = (tid & 1) << 4;       // 0/16 (floats)
    const int bN   = tid & 127;            // B staging: n 0..127
    const int bK   = (tid >> 7) << 4;      // 0/16 (bf16)

    const int frow = l & 15;               // fragment row/col within 16
    const int fk   = (l >> 4) << 3;        // fragment k offset (0,8,16,24)

    f32x4 acc0[4][4], acc1[4][4];
#pragma unroll
    for (int m = 0; m < 4; ++m)
#pragma unroll
        for (int n = 0; n < 4; ++n) {
            acc0[m][n] = f32x4{0.f, 0.f, 0.f, 0.f};
            if constexpr (DUAL) acc1[m][n] = f32x4{0.f, 0.f, 0.f, 0.f};
        }

#pragma unroll
    for (int ph = 0; ph < (DUAL ? 2 : 1); ++ph) {
        const float*  A  = (DUAL && ph) ? A2  : A1;
        const ushort* BH = (DUAL && ph) ? B2H : B1H;
        const ushort* BL = (DUAL && ph) ? B2L : B1L;
        for (int k0 = 0; k0 < K; k0 += 32) {
            // ---- stage A: fp32 -> split bf16 hi/lo into LDS ----
            float f[16];
            int grow = rowBase + sRow;
            if (grow < M) {
                const float4* p = (const float4*)&A[(size_t)grow * lda + k0 + sK];
#pragma unroll
                for (int j = 0; j < 4; ++j) {
                    float4 v = p[j];
                    f[j * 4 + 0] = v.x; f[j * 4 + 1] = v.y;
                    f[j * 4 + 2] = v.z; f[j * 4 + 3] = v.w;
                }
            } else {
#pragma unroll
                for (int j = 0; j < 16; ++j) f[j] = 0.f;
            }
            {
                int base = sRow * LSTR + sK;
#pragma unroll
                for (int j = 0; j < 4; ++j) {
                    ushort4 hv, lv;
                    hv.x = f2bf(f[j * 4 + 0]); lv.x = f2bf(f[j * 4 + 0] - bf2f(hv.x));
                    hv.y = f2bf(f[j * 4 + 1]); lv.y = f2bf(f[j * 4 + 1] - bf2f(hv.y));
                    hv.z = f2bf(f[j * 4 + 2]); lv.z = f2bf(f[j * 4 + 2] - bf2f(hv.z));
                    hv.w = f2bf(f[j * 4 + 3]); lv.w = f2bf(f[j * 4 + 3] - bf2f(hv.w));
                    *(ushort4*)&Ah[base + j * 4] = hv;
                    *(ushort4*)&Al[base + j * 4] = lv;
                }
            }
            // ---- stage B: pre-split bf16 copy (16 bf16/thread/part) ----
            {
                size_t go = (size_t)(n0 + bN) * K + k0 + bK;
                uint4 h0 = *(const uint4*)&BH[go];
                uint4 h1 = *(const uint4*)&BH[go + 8];
                uint4 l0 = *(const uint4*)&BL[go];
                uint4 l1 = *(const uint4*)&BL[go + 8];
                int bb = bN * LSTR + bK;
                *(uint4*)&Bh[bb]     = h0;
                *(uint4*)&Bh[bb + 8] = h1;
                *(uint4*)&Bl[bb]     = l0;
                *(uint4*)&Bl[bb + 8] = l1;
            }
            __syncthreads();
            // ---- fragments + MFMA (3 split products) ----
            bfrag bhF[4], blF[4];
#pragma unroll
            for (int n = 0; n < 4; ++n) {
                int r = (wc + n * 16 + frow) * LSTR + fk;
                bhF[n] = *(const bfrag*)&Bh[r];
                blF[n] = *(const bfrag*)&Bl[r];
            }
#pragma unroll
            for (int m = 0; m < 4; ++m) {
                int r = (wr + m * 16 + frow) * LSTR + fk;
                bfrag ah = *(const bfrag*)&Ah[r];
                bfrag al = *(const bfrag*)&Al[r];
#pragma unroll
                for (int n = 0; n < 4; ++n) {
                    f32x4 a = (DUAL && ph) ? acc1[m][n] : acc0[m][n];
                    a = __builtin_amdgcn_mfma_f32_16x16x32_bf16(ah, bhF[n], a, 0, 0, 0);
                    a = __builtin_amdgcn_mfma_f32_16x16x32_bf16(ah, blF[n], a, 0, 0, 0);
                    a = __builtin_amdgcn_mfma_f32_16x16x32_bf16(al, bhF[n], a, 0, 0, 0);
                    if (DUAL && ph) acc1[m][n] = a; else acc0[m][n] = a;
                }
            }
            __syncthreads();
        }
    }

    // ---- epilogue ----
#pragma unroll
    for (int n = 0; n < 4; ++n) {
        int col = n0 + wc + n * 16 + frow;
        float bb1 = b1[col];
        float bb2 = DUAL ? b2[col] : 0.f;
#pragma unroll
        for (int m = 0; m < 4; ++m) {
            int row0 = rowBase + wr + m * 16 + ((l >> 4) << 2);
#pragma unroll
            for (int q = 0; q < 4; ++q) {
                int row = row0 + q;
                if (row >= M) continue;
                float v;
                if constexpr (DUAL) {
                    v = (acc0[m][n][q] + bb1) * (acc1[m][n][q] + bb2);
                } else {
                    v = acc0[m][n][q] + bb1;
                    if constexpr (SILU) v = silu_f(v);
                }
                C[(size_t)row * ldc + col] = v;
            }
        }
    }
}

// ============================================================================
// o3-post multi-plane split-bf16 MFMA:
//   out[row, OFF + col*NPL + p] = INV128 * sum_u (fij_p[row,u] * g[row,GOFF+u]) W[u,col]
// NPL=1 (s): A = g[:, 0:128] directly (fij unused). NPL=3 (v1), NPL=5 (v2).
// 32-row x 128-col tile per block, 4 waves (2 row x 2 col), NPL acc planes.
// Interleaved output written as NPL consecutive floats per (row,col) ->
// adjacent lanes cover full 64B lines (no partial-line write amplification).
// ============================================================================
template<int NPL, int OFF, int GOFF>
__global__ __launch_bounds__(256) void o3postbf(
    const float* __restrict__ fij, size_t FP,
    const float* __restrict__ g,
    const ushort* __restrict__ WH, const ushort* __restrict__ WL,
    float* __restrict__ out, int M)
{
    __shared__ __align__(16) ushort Ah[NPL * 32 * LSTR];
    __shared__ __align__(16) ushort Al[NPL * 32 * LSTR];
    __shared__ __align__(16) ushort Bh[128 * LSTR];
    __shared__ __align__(16) ushort Bl[128 * LSTR];

    const int tid = threadIdx.x;
    const int l   = tid & 63;
    const int wid = tid >> 6;
    const int wr  = (wid >> 1) << 4;      // wave row offset (0/16)
    const int wc  = (wid & 1) << 6;       // wave col offset (0/64)
    const int rowBase = blockIdx.x << 5;  // 32 rows/block

    const int sR = tid >> 3;              // A staging: row 0..31
    const int sK = (tid & 7) << 2;        // 0..28 (floats)
    const int bN = tid & 127;             // B staging: n 0..127
    const int bK = (tid >> 7) << 4;       // 0/16 (bf16)

    const int frow = l & 15;
    const int fk   = (l >> 4) << 3;

    f32x4 acc[NPL][4];
#pragma unroll
    for (int p = 0; p < NPL; ++p)
#pragma unroll
        for (int n = 0; n < 4; ++n) acc[p][n] = f32x4{0.f, 0.f, 0.f, 0.f};

    for (int k0 = 0; k0 < 128; k0 += 32) {
        // ---- stage A: NPL gated planes -> split bf16 ----
        int grow = rowBase + sR;
        float4 g4 = make_float4(0.f, 0.f, 0.f, 0.f);
        if (grow < M)
            g4 = *(const float4*)&g[(size_t)grow * 384 + GOFF + k0 + sK];
#pragma unroll
        for (int p = 0; p < NPL; ++p) {
            float4 v;
            if constexpr (NPL == 1) {
                v = g4;
            } else {
                float4 f4 = make_float4(0.f, 0.f, 0.f, 0.f);
                if (grow < M)
                    f4 = *(const float4*)&fij[(size_t)p * FP + (size_t)grow * 128 + k0 + sK];
                v = make_float4(f4.x * g4.x, f4.y * g4.y, f4.z * g4.z, f4.w * g4.w);
            }
            ushort4 hv, lv;
            hv.x = f2bf(v.x); lv.x = f2bf(v.x - bf2f(hv.x));
            hv.y = f2bf(v.y); lv.y = f2bf(v.y - bf2f(hv.y));
            hv.z = f2bf(v.z); lv.z = f2bf(v.z - bf2f(hv.z));
            hv.w = f2bf(v.w); lv.w = f2bf(v.w - bf2f(hv.w));
            int base = (p * 32 + sR) * LSTR + sK;
            *(ushort4*)&Ah[base] = hv;
            *(ushort4*)&Al[base] = lv;
        }
        // ---- stage B: pre-split W copy ----
        {
            size_t go = (size_t)bN * 128 + k0 + bK;
            uint4 h0 = *(const uint4*)&WH[go];
            uint4 h1 = *(const uint4*)&WH[go + 8];
            uint4 l0 = *(const uint4*)&WL[go];
            uint4 l1 = *(const uint4*)&WL[go + 8];
            int bb = bN * LSTR + bK;
            *(uint4*)&Bh[bb]     = h0;
            *(uint4*)&Bh[bb + 8] = h1;
            *(uint4*)&Bl[bb]     = l0;
            *(uint4*)&Bl[bb + 8] = l1;
        }
        __syncthreads();
        // ---- fragments + MFMA ----
        bfrag bhF[4], blF[4];
#pragma unroll
        for (int n = 0; n < 4; ++n) {
            int r = (wc + n * 16 + frow) * LSTR + fk;
            bhF[n] = *(const bfrag*)&Bh[r];
            blF[n] = *(const bfrag*)&Bl[r];
        }
#pragma unroll
        for (int p = 0; p < NPL; ++p) {
            int r = (p * 32 + wr + frow) * LSTR + fk;
            bfrag ah = *(const bfrag*)&Ah[r];
            bfrag al = *(const bfrag*)&Al[r];
#pragma unroll
            for (int n = 0; n < 4; ++n) {
                acc[p][n] = __builtin_amdgcn_mfma_f32_16x16x32_bf16(ah, bhF[n], acc[p][n], 0, 0, 0);
                acc[p][n] = __builtin_amdgcn_mfma_f32_16x16x32_bf16(ah, blF[n], acc[p][n], 0, 0, 0);
                acc[p][n] = __builtin_amdgcn_mfma_f32_16x16x32_bf16(al, bhF[n], acc[p][n], 0, 0, 0);
            }
        }
        __syncthreads();
    }

    // ---- epilogue: interleaved contiguous write ----
#pragma unroll
    for (int n = 0; n < 4; ++n) {
        int col = wc + n * 16 + frow;
#pragma unroll
        for (int q = 0; q < 4; ++q) {
            int row = rowBase + wr + ((l >> 4) << 2) + q;
            if (row >= M) continue;
            float* po = &out[(size_t)row * ND + OFF + col * NPL];
#pragma unroll
            for (int p = 0; p < NPL; ++p)
                po[p] = acc[p][n][q] * INV128;
        }
    }
}

// ============================================================================
// One-time weight split+transpose: W[K][N] fp32 -> H/L [N][K] bf16.
// grid.y selects matrix; out is one packed ushort arena.
// ============================================================================
__global__ void wsplit_kernel(
    const float* __restrict__ W0, const float* __restrict__ W1,
    const float* __restrict__ W2, const float* __restrict__ W3,
    const float* __restrict__ W4, const float* __restrict__ W5,
    const float* __restrict__ W6, const float* __restrict__ W7,
    const float* __restrict__ W8,
    ushort* __restrict__ out)
{
    int m = blockIdx.y;
    const float* W; int K, N; size_t off;
    switch (m) {
        case 0:  W = W0; K = 128; N = 1408; off = 0;        break;
        case 1:  W = W1; K = 128; N = 1408; off = 360448;   break;
        case 2:  W = W2; K = 384; N = 384;  off = 720896;   break;
        case 3:  W = W3; K = 384; N = 384;  off = 1015808;  break;
        case 4:  W = W4; K = 384; N = 384;  off = 1310720;  break;
        case 5:  W = W5; K = 384; N = 384;  off = 1605632;  break;
        case 6:  W = W6; K = 128; N = 128;  off = 1900544;  break;
        case 7:  W = W7; K = 128; N = 128;  off = 1933312;  break;
        default: W = W8; K = 128; N = 128;  off = 1966080;  break;
    }
    int idx = blockIdx.x * 256 + threadIdx.x;
    if (idx >= K * N) return;
    int k = idx / N, n = idx - k * N;
    float v = W[idx];
    ushort h  = f2bf(v);
    ushort lo = f2bf(v - bf2f(h));
    size_t KN = (size_t)K * N;
    out[off + (size_t)n * K + k]      = h;
    out[off + KN + (size_t)n * K + k] = lo;
}

// ============================================================================
// 128x128-tile fp32 GEMM (kept for es1 / er1 / o3 pre).
// ============================================================================
template<int AMODE, int OMODE, bool SILU, bool FMUL, bool O3S>
__global__ __launch_bounds__(256) void gemm128(
    const float* __restrict__ A, int lda,
    const float* __restrict__ B, int ldb,
    const float* __restrict__ W1p, const float* __restrict__ W2p,
    const float* __restrict__ bias, const float* __restrict__ M2,
    float* __restrict__ C, int ldc, int M, int K,
    const float* __restrict__ xg, const int* __restrict__ ei,
    const float* __restrict__ dots)
{
    __shared__ float Ast[32][132];
    __shared__ float Bs[32][132];

    const int tid = threadIdx.x;
    const int tx = tid & 15, ty = tid >> 4;
    const int rowBase = blockIdx.y << 7;
    const int n0 = blockIdx.x << 7;
    const int z = blockIdx.z;

    int off = 0, stride = 1;
    if constexpr (AMODE == 2 || AMODE == 3 || AMODE == 4 || OMODE == 1 || O3S) {
        if (z == 0)      { off = 0;             stride = 1; }
        else if (z < 4)  { off = 128 + (z - 1); stride = 3; }
        else             { off = 512 + (z - 4); stride = 5; }
    }
    const float* Bz = B;
    if constexpr (AMODE >= 2) {   // o3 weight select by l
        if (z >= 1 && z < 4) Bz = W1p;
        else if (z >= 4)     Bz = W2p;
    }
    const float* Ab = A;
    if constexpr (AMODE == 3 || AMODE == 4) Ab = A + (size_t)z * M * lda;
    float* Cb = C;
    if constexpr (OMODE == 2) Cb = C + (size_t)z * M * ldc;

    float acc[2][2][4][4] = {};

    for (int k0 = 0; k0 < K; k0 += 32) {
        // ---- stage A (transposed into LDS) ----
#pragma unroll
        for (int i = 0; i < 4; ++i) {
            int f4 = tid + (i << 8);          // 0..1023
            int row = f4 >> 3;                // 0..127
            int kq  = (f4 & 7) << 2;          // 0,4,..,28
            int grow = rowBase + row, gk = k0 + kq;
            float4 v = make_float4(0.f, 0.f, 0.f, 0.f);
            if (grow < M) {
                if constexpr (AMODE == 0 || AMODE == 3) {
                    if (gk + 4 <= K) {
                        v = *(const float4*)&Ab[(size_t)grow * lda + gk];
                    } else {
                        float t[4] = {0.f, 0.f, 0.f, 0.f};
#pragma unroll
                        for (int j = 0; j < 4; ++j)
                            if (gk + j < K) t[j] = Ab[(size_t)grow * lda + gk + j];
                        v = make_float4(t[0], t[1], t[2], t[3]);
                    }
                } else if constexpr (AMODE == 1) {
                    if (gk < 128)
                        v = *(const float4*)&xg[(size_t)ei[grow] * ND + gk];
                    else if (gk < 256)
                        v = *(const float4*)&xg[(size_t)ei[NEDGES + grow] * ND + (gk - 128)];
                    else
                        v = *(const float4*)&dots[(size_t)grow * 256 + (gk - 256)];
                } else if constexpr (AMODE == 2) {  // strided component from interleaved rows
                    const float* p = &Ab[(size_t)grow * ND + off];
                    v.x = p[(gk + 0) * stride];
                    v.y = p[(gk + 1) * stride];
                    v.z = p[(gk + 2) * stride];
                    v.w = p[(gk + 3) * stride];
                } else {  // AMODE 4: gated plane read
                    int gsel = (z == 0) ? 0 : (z < 4 ? 128 : 256);
                    float4 vg = *(const float4*)&xg[(size_t)grow * 384 + gsel + gk];
                    if (z == 0) {
                        v = vg;
                    } else {
                        float4 vf = *(const float4*)&Ab[(size_t)grow * lda + gk];
                        v = make_float4(vf.x * vg.x, vf.y * vg.y,
                                        vf.z * vg.z, vf.w * vg.w);
                    }
                }
            }
            Ast[kq + 0][row] = v.x;
            Ast[kq + 1][row] = v.y;
            Ast[kq + 2][row] = v.z;
            Ast[kq + 3][row] = v.w;
        }
        // ---- stage B ----
#pragma unroll
        for (int i = 0; i < 4; ++i) {
            int f4 = tid + (i << 8);
            int bk = f4 >> 5;                 // 0..31
            int nq = (f4 & 31) << 2;          // 0..124
            float4 v = make_float4(0.f, 0.f, 0.f, 0.f);
            if (k0 + bk < K)
                v = *(const float4*)&Bz[(size_t)(k0 + bk) * ldb + n0 + nq];
            *(float4*)&Bs[bk][nq] = v;
        }
        __syncthreads();
#pragma unroll
        for (int kk = 0; kk < 32; ++kk) {
            float4 a0 = *(const float4*)&Ast[kk][(ty << 2)];
            float4 a1 = *(const float4*)&Ast[kk][64 + (ty << 2)];
            float4 b0 = *(const float4*)&Bs[kk][(tx << 2)];
            float4 b1 = *(const float4*)&Bs[kk][64 + (tx << 2)];
            float ar[2][4] = {{a0.x, a0.y, a0.z, a0.w}, {a1.x, a1.y, a1.z, a1.w}};
            float br[2][4] = {{b0.x, b0.y, b0.z, b0.w}, {b1.x, b1.y, b1.z, b1.w}};
#pragma unroll
            for (int h = 0; h < 2; ++h)
#pragma unroll
                for (int g = 0; g < 2; ++g)
#pragma unroll
                    for (int ii = 0; ii < 4; ++ii)
#pragma unroll
                        for (int jj = 0; jj < 4; ++jj)
                            acc[h][g][ii][jj] = fmaf(ar[h][ii], br[g][jj], acc[h][g][ii][jj]);
        }
        __syncthreads();
    }

    // ---- epilogue ----
#pragma unroll
    for (int h = 0; h < 2; ++h) {
#pragma unroll
        for (int ii = 0; ii < 4; ++ii) {
            int row = rowBase + (h << 6) + (ty << 2) + ii;
            if (row >= M) continue;
#pragma unroll
            for (int g = 0; g < 2; ++g) {
                int colq = n0 + (g << 6) + (tx << 2);
                float o[4];
#pragma unroll
                for (int jj = 0; jj < 4; ++jj) {
                    float v = acc[h][g][ii][jj];
                    int col = colq + jj;
                    if constexpr (O3S) {
                        v *= INV128;
                        if (bias && z == 0) v += bias[col];
                    } else {
                        if (bias) v += bias[col];
                    }
                    if constexpr (SILU) v = silu_f(v);
                    if constexpr (FMUL) v *= M2[(size_t)row * ldc + col];
                    o[jj] = v;
                }
                if constexpr (OMODE == 1) {
                    float* p = &Cb[(size_t)row * ND + off];
#pragma unroll
                    for (int jj = 0; jj < 4; ++jj) p[(colq + jj) * stride] = o[jj];
                } else {
                    *(float4*)&Cb[(size_t)row * ldc + colq] =
                        make_float4(o[0], o[1], o[2], o[3]);
                }
            }
        }
    }
}

// ============================================================================
// dots for s0 (reads interleaved input x)
// ============================================================================
__global__ void dots_kernel(const float* __restrict__ x, const int* __restrict__ ei,
                            float* __restrict__ dots)
{
    int idx = blockIdx.x * 256 + threadIdx.x;
    int e = idx >> 8, t = idx & 255;
    if (e >= NEDGES) return;
    const float* ps = x + (size_t)ei[e] * ND;
    const float* pd = x + (size_t)ei[NEDGES + e] * ND;
    float v;
    if (t < 128) {
        int u = 128 + t * 3;
        v = (ps[u] * pd[u] + ps[u + 1] * pd[u + 1] + ps[u + 2] * pd[u + 2]) * CK1;
    } else {
        int u = 512 + (t - 128) * 5;
        v = (ps[u] * pd[u] + ps[u + 1] * pd[u + 1] + ps[u + 2] * pd[u + 2]
             + ps[u + 3] * pd[u + 3] + ps[u + 4] * pd[u + 4]) * CK2;
    }
    dots[idx] = v;
}

// ============================================================================
// f0 = [s, ||v1||_c, ||v2||_c] from PLANE layout (node side)
// ============================================================================
__global__ void f0_kernel(const float* __restrict__ in, float* __restrict__ f0, int M)
{
    int idx = blockIdx.x * 256 + threadIdx.x;
    int r = idx / 384, t = idx - r * 384;
    if (r >= M) return;
    size_t P = (size_t)M * 128;
    const float* p = in + (size_t)r * 128;
    float v;
    if (t < 128) v = p[t];
    else if (t < 256) {
        int u = t - 128;
        float x1 = p[P + u], x2 = p[2 * P + u], x3 = p[3 * P + u];
        v = sqrtf(x1 * x1 + x2 * x2 + x3 * x3);
    } else {
        int u = t - 256;
        float x1 = p[4 * P + u], x2 = p[5 * P + u], x3 = p[6 * P + u],
              x4 = p[7 * P + u], x5 = p[8 * P + u];
        v = sqrtf(x1 * x1 + x2 * x2 + x3 * x3 + x4 * x4 + x5 * x5);
    }
    f0[(size_t)r * 384 + t] = v;
}

// gate in place on PLANE layout (node side). grid: (ceil(M*128/256), 9)
__global__ void gate_kernel(float* __restrict__ xp, const float* __restrict__ g, int M)
{
    int t = blockIdx.x * 256 + threadIdx.x;
    if (t >= M * 128) return;
    int z = blockIdx.y;
    int r = t >> 7, u = t & 127;
    float* p = xp + (size_t)z * M * 128 + t;
    const float* gr = g + (size_t)r * 384;
    if (z == 0)      *p = gr[u];
    else if (z < 4)  *p *= gr[128 + u];
    else             *p *= gr[256 + u];
}

// ============================================================================
// Wigner TP, plane layout in (xp) and out (fij). 2 edges per block.
// Emits f0 = [o_s, ||o1||, ||o2||] directly.
// ============================================================================
__global__ __launch_bounds__(256) void tp_kernel(
    const float* __restrict__ xp, const int* __restrict__ ei,
    const float* __restrict__ tpw, float* __restrict__ fij,
    float* __restrict__ f0, int e0, int ec)
{
    int le = blockIdx.x * 2 + (threadIdx.x >> 7);
    int u = threadIdx.x & 127;
    if (le >= ec) return;
    int e = e0 + le;
    const size_t NP = (size_t)NNODES * 128;
    const float* ps = xp + (size_t)ei[e] * 128 + u;
    const float* pd = xp + (size_t)ei[NEDGES + e] * 128 + u;

    float ss = ps[0], sd = pd[0];
    float a0 = ps[NP],     a1 = ps[2 * NP], a2 = ps[3 * NP];
    float b0 = pd[NP],     b1 = pd[2 * NP], b2 = pd[3 * NP];
    float c0 = ps[4 * NP], c1 = ps[5 * NP], c2 = ps[6 * NP],
          c3 = ps[7 * NP], c4 = ps[8 * NP];
    float d0 = pd[4 * NP], d1 = pd[5 * NP], d2 = pd[6 * NP],
          d3 = pd[7 * NP], d4 = pd[8 * NP];

    const float* w = tpw + (size_t)le * WNW + u;
    float w0 = w[0],    w1 = w[128],  w2 = w[256],  w3 = w[384],  w4 = w[512];
    float w5 = w[640],  w6 = w[768],  w7 = w[896],  w8 = w[1024], w9 = w[1152];
    float w10 = w[1280];

    float dab = a0 * b0 + a1 * b1 + a2 * b2;
    float dcd = c0 * d0 + c1 * d1 + c2 * d2 + c3 * d3 + c4 * d4;

    float o_s = PW0 * (w0 * ss * sd + w4 * CK1 * dab + w9 * CK2 * dcd);

    float R0 = A0A * a0 * d2 + A2C * (a1 * d1 + a2 * d0 - a0 * d4);
    float R1 = A0B * a1 * d2 + A2C * (a0 * d1 + a2 * d3);
    float R2 = A0A * a2 * d2 + A2C * (a1 * d3 + a0 * d0 + a2 * d4);
    float U0 = A0A * b0 * c2 + A2C * (b1 * c1 + b2 * c0 - b0 * c4);
    float U1 = A0B * b1 * c2 + A2C * (b0 * c1 + b2 * c3);
    float U2 = A0A * b2 * c2 + A2C * (b1 * c3 + b0 * c0 + b2 * c4);
    float o1_0 = PW1 * (CK1 * (w1 * ss * b0 + w3 * a0 * sd) + w6 * R0 + w8 * U0);
    float o1_1 = PW1 * (CK1 * (w1 * ss * b1 + w3 * a1 * sd) + w6 * R1 + w8 * U1);
    float o1_2 = PW1 * (CK1 * (w1 * ss * b2 + w3 * a2 * sd) + w6 * R2 + w8 * U2);

    float S0 = A2C * (a0 * b2 + a2 * b0);
    float S1 = A2C * (a0 * b1 + a1 * b0);
    float S2 = A0A * (a0 * b0 + a2 * b2) + A0B * a1 * b1;
    float S3 = A2C * (a1 * b2 + a2 * b1);
    float S4 = A2C * (a2 * b2 - a0 * b0);
    float V0 = -B2C * (c0 * d2 + c2 * d0) + B3C * (c1 * d3 + c3 * d1);
    float V1 =  B3C * (c0 * d3 + c3 * d0) - B3C * (c1 * d4 + c4 * d1)
              + B1C * (c1 * d2 + c2 * d1);
    float V2 = -B2C * (c0 * d0 + c4 * d4) + B1C * (c1 * d1 + c3 * d3) + B2C * c2 * d2;
    float V3 =  B3C * (c0 * d1 + c1 * d0) + B3C * (c3 * d4 + c4 * d3)
              + B1C * (c2 * d3 + c3 * d2);
    float V4 = -B2C * (c2 * d4 + c4 * d2) - B3C * c1 * d1 + B3C * c3 * d3;
    float o2_0 = PW2 * (CK2 * (w2 * ss * d0 + w7 * c0 * sd) + w5 * S0 + w10 * V0);
    float o2_1 = PW2 * (CK2 * (w2 * ss * d1 + w7 * c1 * sd) + w5 * S1 + w10 * V1);
    float o2_2 = PW2 * (CK2 * (w2 * ss * d2 + w7 * c2 * sd) + w5 * S2 + w10 * V2);
    float o2_3 = PW2 * (CK2 * (w2 * ss * d3 + w7 * c3 * sd) + w5 * S3 + w10 * V3);
    float o2_4 = PW2 * (CK2 * (w2 * ss * d4 + w7 * c4 * sd) + w5 * S4 + w10 * V4);

    size_t FP = (size_t)ec * 128;
    float* po = fij + (size_t)le * 128 + u;
    po[0] = o_s;
    po[FP] = o1_0;     po[2 * FP] = o1_1; po[3 * FP] = o1_2;
    po[4 * FP] = o2_0; po[5 * FP] = o2_1; po[6 * FP] = o2_2;
    po[7 * FP] = o2_3; po[8 * FP] = o2_4;

    // fused f0 = [s, ||v1||, ||v2||]
    float n1 = sqrtf(o1_0 * o1_0 + o1_1 * o1_1 + o1_2 * o1_2);
    float n2 = sqrtf(o2_0 * o2_0 + o2_1 * o2_1 + o2_2 * o2_2
                     + o2_3 * o2_3 + o2_4 * o2_4);
    float* pf = f0 + (size_t)le * 384;
    pf[u] = o_s;
    pf[128 + u] = n1;
    pf[256 + u] = n2;
}

// ============================================================================
extern "C" void kernel_launch(void* const* d_in, const int* in_sizes, int n_in,
                              void* d_out, int out_size, void* d_ws, size_t ws_size,
                              hipStream_t stream)
{
    const float* x         = (const float*)d_in[0];
    const float* edge_attr = (const float*)d_in[1];
    const int*   ei        = (const int*)  d_in[2];
    const float* W_pre0    = (const float*)d_in[3];
    const float* W_pre1    = (const float*)d_in[4];
    const float* W_pre2    = (const float*)d_in[5];
    const float* b_pre0    = (const float*)d_in[6];
    const float* ngpre_W1  = (const float*)d_in[7];
    const float* ngpre_b1  = (const float*)d_in[8];
    const float* ngpre_W2  = (const float*)d_in[9];
    const float* ngpre_b2  = (const float*)d_in[10];
    const float* es_W1     = (const float*)d_in[11];
    const float* es_b1     = (const float*)d_in[12];
    const float* es_W2     = (const float*)d_in[13];
    const float* es_b2     = (const float*)d_in[14];
    const float* er_W1     = (const float*)d_in[15];
    const float* er_b1     = (const float*)d_in[16];
    const float* er_W2     = (const float*)d_in[17];
    const float* er_b2     = (const float*)d_in[18];
    const float* ngpost_W1 = (const float*)d_in[19];
    const float* ngpost_b1 = (const float*)d_in[20];
    const float* ngpost_W2 = (const float*)d_in[21];
    const float* ngpost_b2 = (const float*)d_in[22];
    const float* W_post0   = (const float*)d_in[23];
    const float* W_post1   = (const float*)d_in[24];
    const float* W_post2   = (const float*)d_in[25];
    float* out = (float*)d_out;
    float* ws  = (float*)d_ws;

    // fixed workspace: xp planes (9*N*128), hes, her, bf16 weight splits
    float* xp    = ws;
    float* hes   = ws + (size_t)9 * NNODES * 128;               // 11.52M
    float* her   = hes + (size_t)NEDGES * 128;                  // +6.4M
    ushort* wsp  = (ushort*)(her + (size_t)NEDGES * 128);       // ~2.0M ushorts
    const ushort* esW2tH   = wsp;
    const ushort* esW2tL   = wsp + 180224;
    const ushort* erW2tH   = wsp + 360448;
    const ushort* erW2tL   = wsp + 540672;
    const ushort* preW1H   = wsp + 720896;
    const ushort* preW1L   = wsp + 868352;
    const ushort* preW2H   = wsp + 1015808;
    const ushort* preW2L   = wsp + 1163264;
    const ushort* postW1H  = wsp + 1310720;
    const ushort* postW1L  = wsp + 1458176;
    const ushort* postW2H  = wsp + 1605632;
    const ushort* postW2L  = wsp + 1753088;
    const ushort* o3pW0H   = wsp + 1900544;
    const ushort* o3pW0L   = wsp + 1916928;
    const ushort* o3pW1H   = wsp + 1933312;
    const ushort* o3pW1L   = wsp + 1949696;
    const ushort* o3pW2H   = wsp + 1966080;
    const ushort* o3pW2L   = wsp + 1982464;
    float* arena = her + (size_t)NEDGES * 128 + 999424;         // 25.32M fixed

    long ws_floats = (long)(ws_size / 4);
    long arena_f = ws_floats - 25319424L;
    long ec0 = arena_f / 2944;                                  // tpw+fij+f0 slots
    if (ec0 > NEDGES) ec0 = NEDGES;
    if (ec0 < 1) ec0 = 1;
    int NC = (int)((NEDGES + ec0 - 1) / ec0);
    int Ec = (NEDGES + NC - 1) / NC;

    float* dots = arena;                                        // pre-loop use

    // ---- one-time weight split/transpose ----
    wsplit_kernel<<<dim3(704, 9), 256, 0, stream>>>(
        es_W2, er_W2, ngpre_W1, ngpre_W2, ngpost_W1, ngpost_W2,
        W_post0, W_post1, W_post2, wsp);

    // ---- edge hidden MLPs (full E) ----
    dots_kernel<<<NEDGES, 256, 0, stream>>>(x, ei, dots);

    dim3 gE(1, (NEDGES + 127) / 128);
    gemm128<1, 0, true, false, false><<<gE, 256, 0, stream>>>(
        nullptr, 0, es_W1, 128, nullptr, nullptr, es_b1, nullptr,
        hes, 128, NEDGES, 512, x, ei, dots);
    gemm128<0, 0, true, false, false><<<gE, 256, 0, stream>>>(
        edge_attr, EDIM, er_W1, 128, nullptr, nullptr, er_b1, nullptr,
        her, 128, NEDGES, EDIM, nullptr, nullptr, nullptr);

    // ---- node pre: xp = norm_gate(o3_linear(x))  [plane layout] ----
    dim3 gO3p(1, (NNODES + 127) / 128, 9);
    gemm128<2, 2, false, false, true><<<gO3p, 256, 0, stream>>>(
        x, 0, W_pre0, 128, W_pre1, W_pre2, b_pre0, nullptr,
        xp, 128, NNODES, 128, nullptr, nullptr, nullptr);

    float* f0n = arena;
    float* hb  = f0n + (size_t)NNODES * 384;
    float* gb  = hb + (size_t)NNODES * 384;
    f0_kernel<<<((size_t)NNODES * 384 + 255) / 256, 256, 0, stream>>>(xp, f0n, NNODES);
    dim3 gNGp(3, (NNODES + 127) / 128);
    gemmbf<false, true><<<gNGp, 256, 0, stream>>>(
        f0n, 384, preW1H, preW1L, ngpre_b1,
        nullptr, nullptr, nullptr, nullptr,
        hb, 384, NNODES, 384);
    gemmbf<false, false><<<gNGp, 256, 0, stream>>>(
        hb, 384, preW2H, preW2L, ngpre_b2,
        nullptr, nullptr, nullptr, nullptr,
        gb, 384, NNODES, 384);
    dim3 gGp((NNODES * 128 + 255) / 256, 9);
    gate_kernel<<<gGp, 256, 0, stream>>>(xp, gb, NNODES);

    // ---- edge chunks ----
    for (int c = 0; c < NC; ++c) {
        int e0 = c * Ec;
        int ec = NEDGES - e0; if (ec > Ec) ec = Ec;
        if (ec <= 0) break;

        float* tpwc = arena;
        float* fijc = tpwc + (size_t)Ec * 1408;
        float* f0p  = fijc + (size_t)Ec * 1152;

        // fused split-bf16 MFMA: tpw = (hes@es_W2 + es_b2) * (her@er_W2 + er_b2)
        dim3 gW(11, (ec + 127) / 128);
        gemmbf<true, false><<<gW, 256, 0, stream>>>(
            hes + (size_t)e0 * 128, 128, esW2tH, esW2tL, es_b2,
            her + (size_t)e0 * 128, erW2tH, erW2tL, er_b2,
            tpwc, WNW, ec, 128);

        // TP + fused f0
        tp_kernel<<<(ec + 1) / 2, 256, 0, stream>>>(xp, ei, tpwc, fijc, f0p, e0, ec);

        // tpw dead: reuse its slot for h1/g (2*384 = 768 <= 1408)
        float* h1p = tpwc;
        float* gp  = tpwc + (size_t)Ec * 384;
        dim3 gNG(3, (ec + 127) / 128);
        gemmbf<false, true><<<gNG, 256, 0, stream>>>(
            f0p, 384, postW1H, postW1L, ngpost_b1,
            nullptr, nullptr, nullptr, nullptr,
            h1p, 384, ec, 384);
        gemmbf<false, false><<<gNG, 256, 0, stream>>>(
            h1p, 384, postW2H, postW2L, ngpost_b2,
            nullptr, nullptr, nullptr, nullptr,
            gp, 384, ec, 384);

        // o3-post: multi-plane MFMA, gate fused, contiguous interleaved writes
        size_t FPc = (size_t)ec * 128;
        int nb = (ec + 31) / 32;
        o3postbf<1, 0, 0><<<nb, 256, 0, stream>>>(
            nullptr, 0, gp, o3pW0H, o3pW0L, out + (size_t)e0 * ND, ec);
        o3postbf<3, 128, 128><<<nb, 256, 0, stream>>>(
            fijc + FPc, FPc, gp, o3pW1H, o3pW1L, out + (size_t)e0 * ND, ec);
        o3postbf<5, 512, 256><<<nb, 256, 0, stream>>>(
            fijc + 4 * FPc, FPc, gp, o3pW2H, o3pW2L, out + (size_t)e0 * ND, ec);
    }
}